// Round 8
// baseline (457.481 us; speedup 1.0000x reference)
//
#include <hip/hip_runtime.h>

typedef __bf16 bf16x4 __attribute__((ext_vector_type(4)));
typedef __bf16 bf16x8 __attribute__((ext_vector_type(8)));
typedef float  f32x4  __attribute__((ext_vector_type(4)));

#define HWSZ 4096
#define CCH  256
#define LOG2E 1.44269504088896340736f

__device__ __forceinline__ float exp2_fast(float x) {
#if __has_builtin(__builtin_amdgcn_exp2f)
  return __builtin_amdgcn_exp2f(x);
#else
  return exp2f(x);
#endif
}

// barrier that only drains LDS ops (lgkmcnt), letting global loads stay in
// flight across the barrier. Safe when the barrier only protects LDS state.
__device__ __forceinline__ void bar_lgkm() {
  asm volatile("s_waitcnt lgkmcnt(0)" ::: "memory");
  __builtin_amdgcn_s_barrier();
}

// stage 16B per lane into LDS; lane's data lands at lds_base + lane*16B
__device__ __forceinline__ void stage16(const __bf16* g, __bf16* ldsBase) {
#if __has_builtin(__builtin_amdgcn_global_load_lds)
  __builtin_amdgcn_global_load_lds(
      (const __attribute__((address_space(1))) void*)g,
      (__attribute__((address_space(3))) void*)ldsBase, 16, 0, 0);
#else
  int lane = threadIdx.x & 63;
  *(bf16x8*)(ldsBase + lane * 8) = *(const bf16x8*)g;
#endif
}

// XOR swizzle for 32-elem-row LDS tiles: phys 16B-chunk = logical ^ ((row>>1)&3).
#define SWZ_STAGE(lane) ((((lane) & 3) ^ (((lane) >> 3) & 3)) * 8)
#define SWZ_READ(quad, lane) ((((quad) ^ (((lane) >> 1) & 3))) * 8)

// ---------------------------------------------------------------------------
// Merged conv3x3 GEMM, implicit-im2col (128x128x32 MFMA): by<8 -> A=AL
// (Qs,Ks,Vs,Qc from Fl), else A=AV (Kc,Vc from Fv). B staged directly from
// Xt [img][4096][256]: tap t=k0>>8 (dy,dx), border lanes read a zero page.
// ---------------------------------------------------------------------------
__global__ __launch_bounds__(256)
void gemm_conv(const __bf16* __restrict__ AL, const __bf16* __restrict__ AV,
               const __bf16* __restrict__ Xt, const __bf16* __restrict__ zp,
               __bf16* __restrict__ qst, __bf16* __restrict__ kst,
               __bf16* __restrict__ vs,  __bf16* __restrict__ qct,
               __bf16* __restrict__ kct, __bf16* __restrict__ vc,
               const float* __restrict__ bqs, const float* __restrict__ bks,
               const float* __restrict__ bvs, const float* __restrict__ bqc,
               const float* __restrict__ bkc, const float* __restrict__ bvc)
{
  __shared__ __align__(16) __bf16 smem[8192];
  __bf16* As = smem;
  __bf16* Bs = smem + 4096;

  const int tid  = threadIdx.x;
  const int lane = tid & 63;
  const int w    = tid >> 6;
  const int wm   = (w >> 1) * 64;
  const int wn   = (w & 1) * 64;
  const int z    = blockIdx.z;
  const int by   = blockIdx.y;
  const int bn   = blockIdx.x * 128;
  const int K    = 2304;

  const bool isL = (by < 8);
  const int bm = (isL ? by : by - 8) * 128;
  const __bf16* Ab = isL ? AL : AV;
  const __bf16* Xb = Xt + (long)((isL ? 0 : 2) + z) * (HWSZ * CCH);

  f32x4 acc[4][4] = {};
  const int srow = lane >> 2;
  const int skc  = SWZ_STAGE(lane);
  const int quad = lane >> 4, l15 = lane & 15;
  const int rdo  = SWZ_READ(quad, lane);

  for (int k0 = 0; k0 < K; k0 += 32) {
    const int t9  = k0 >> 8;                 // tap 0..8 (uniform per k0)
    const int dy  = t9 / 3 - 1;
    const int dx  = t9 - (t9 / 3) * 3 - 1;
    const int off = dy * 64 + dx;
    const int ci0 = k0 & 255;
#pragma unroll
    for (int j = 0; j < 2; ++j) {
      int rbase = w * 32 + j * 16;
      stage16(Ab + (long)(bm + rbase + srow) * K + k0 + skc, As + rbase * 32);
    }
#pragma unroll
    for (int j = 0; j < 2; ++j) {
      int rbase = w * 32 + j * 16;
      int p = bn + rbase + srow;
      int y = p >> 6, x = p & 63;
      bool valid = ((unsigned)(y + dy) < 64u) && ((unsigned)(x + dx) < 64u);
      const __bf16* src = valid ? (Xb + (long)(p + off) * CCH + ci0 + skc) : zp;
      stage16(src, Bs + rbase * 32);
    }
    __syncthreads();
    bf16x8 af[4], bfr[4];
#pragma unroll
    for (int t = 0; t < 4; ++t)
      af[t] = *(const bf16x8*)(As + (wm + t * 16 + l15) * 32 + rdo);
#pragma unroll
    for (int t = 0; t < 4; ++t)
      bfr[t] = *(const bf16x8*)(Bs + (wn + t * 16 + l15) * 32 + rdo);
#pragma unroll
    for (int mt = 0; mt < 4; ++mt)
#pragma unroll
      for (int nt = 0; nt < 4; ++nt)
        acc[mt][nt] = __builtin_amdgcn_mfma_f32_16x16x32_bf16(af[mt], bfr[nt], acc[mt][nt], 0, 0, 0);
    __syncthreads();
  }

#pragma unroll
  for (int mt = 0; mt < 4; ++mt) {
#pragma unroll
    for (int nt = 0; nt < 4; ++nt) {
#pragma unroll
      for (int r = 0; r < 4; ++r) {
        int m = bm + wm + mt * 16 + quad * 4 + r;
        int n = bn + wn + nt * 16 + l15;
        int g = m >> 8, mm = m & 255;
        const float* bias; __bf16* op; bool vlay;
        if (isL) {
          bias = (g == 0) ? bqs : (g == 1) ? bks : (g == 2) ? bvs : bqc;
          op   = (g == 0) ? qst : (g == 1) ? kst : (g == 2) ? vs  : qct;
          vlay = (g == 2);
        } else {
          bias = g ? bvc : bkc;
          op   = g ? vc  : kct;
          vlay = (g == 1);
        }
        float vv = acc[mt][nt][r] + bias[mm];
        if (vlay) op[(long)z * 1048576 + (long)mm * HWSZ + n] = (__bf16)vv;   // V: [c,p]
        else      op[(long)z * 1048576 + (long)n * CCH + mm] = (__bf16)vv;    // Q/K: [p,c]
      }
    }
  }
}

// ---------------------------------------------------------------------------
// qk_stats: partial column-softmax stats over HALF the i-range.
// 1-D grid 512: lid -> (g: z,br | ih | qb). Kres stride 260 (conflict-free).
// ---------------------------------------------------------------------------
__global__ __launch_bounds__(256)
void qk_stats(const __bf16* __restrict__ qs, const __bf16* __restrict__ qc,
              const __bf16* __restrict__ ks, const __bf16* __restrict__ kc,
              float* __restrict__ pm, float* __restrict__ pl)
{
  __shared__ __align__(16) __bf16 Kres[64 * 260];
  __shared__ float wm_[4][64], wl_[4][64];

  const int tid = threadIdx.x, lane = tid & 63, w = tid >> 6;
  const int quad = lane >> 4, l15 = lane & 15;
  const int lid = blockIdx.x;
  const int g = lid & 3;
  const int z = g & 1, br = g >> 1;
  const int ih = (lid >> 2) & 1;
  const int qb = (lid >> 3) * 64;
  const __bf16* Qt = (br ? qc : qs) + (long)z * 1048576;
  const __bf16* Kt = (br ? kc : ks) + (long)z * 1048576;

  for (int idx = tid; idx < 2048; idx += 256) {
    int r = idx >> 5, c8 = (idx & 31) * 8;
    *(bf16x8*)(Kres + r * 260 + c8) = *(const bf16x8*)(Kt + (long)(qb + r) * 256 + c8);
  }
  __syncthreads();

  float rm[4], rl[4];
#pragma unroll
  for (int nt = 0; nt < 4; ++nt) { rm[nt] = -3.0e38f; rl[nt] = 0.f; }

  for (int it = 0; it < 8; ++it) {
    const int i0 = ih * 2048 + it * 256 + w * 64;
    f32x4 accS[4][4] = {};
#pragma unroll
    for (int cs = 0; cs < 256; cs += 32) {
      bf16x8 a[4], b[4];
#pragma unroll
      for (int mt = 0; mt < 4; ++mt)
        a[mt] = *(const bf16x8*)(Qt + (long)(i0 + mt * 16 + l15) * 256 + cs + quad * 8);
#pragma unroll
      for (int nt = 0; nt < 4; ++nt)
        b[nt] = *(const bf16x8*)(Kres + (nt * 16 + l15) * 260 + cs + quad * 8);
      __builtin_amdgcn_s_setprio(1);
#pragma unroll
      for (int mt = 0; mt < 4; ++mt)
#pragma unroll
        for (int nt = 0; nt < 4; ++nt)
          accS[mt][nt] = __builtin_amdgcn_mfma_f32_16x16x32_bf16(a[mt], b[nt], accS[mt][nt], 0, 0, 0);
      __builtin_amdgcn_s_setprio(0);
    }
#pragma unroll
    for (int nt = 0; nt < 4; ++nt) {
      float mx = -3.0e38f;
#pragma unroll
      for (int mt = 0; mt < 4; ++mt)
#pragma unroll
        for (int r = 0; r < 4; ++r) mx = fmaxf(mx, accS[mt][nt][r]);
      float sl = 0.f;
#pragma unroll
      for (int mt = 0; mt < 4; ++mt)
#pragma unroll
        for (int r = 0; r < 4; ++r) sl += exp2_fast((accS[mt][nt][r] - mx) * LOG2E);
#pragma unroll
      for (int d = 16; d <= 32; d <<= 1) {
        float om = __shfl_xor(mx, d, 64);
        float ol = __shfl_xor(sl, d, 64);
        float nm = fmaxf(mx, om);
        sl = sl * exp2_fast((mx - nm) * LOG2E) + ol * exp2_fast((om - nm) * LOG2E);
        mx = nm;
      }
      float nm = fmaxf(rm[nt], mx);
      rl[nt] = rl[nt] * exp2_fast((rm[nt] - nm) * LOG2E) + sl * exp2_fast((mx - nm) * LOG2E);
      rm[nt] = nm;
    }
  }
  if (lane < 16) {
#pragma unroll
    for (int nt = 0; nt < 4; ++nt) { wm_[w][nt * 16 + lane] = rm[nt]; wl_[w][nt * 16 + lane] = rl[nt]; }
  }
  __syncthreads();
  if (tid < 64) {
    float m = -3.0e38f;
#pragma unroll
    for (int ww = 0; ww < 4; ++ww) m = fmaxf(m, wm_[ww][tid]);
    float l = 0.f;
#pragma unroll
    for (int ww = 0; ww < 4; ++ww)
      l += wl_[ww][tid] * exp2_fast((wm_[ww][tid] - m) * LOG2E);
    long o = ((long)ih * 4 + br * 2 + z) * 4096 + qb + tid;
    pm[o] = m;
    pl[o] = l;
  }
}

// combine the two i-half partials -> final m, 1/l. grid (16, 4 zbr), 256 thr.
__global__ void stats_combine2(const float* __restrict__ pm, const float* __restrict__ pl,
                               float* __restrict__ mst, float* __restrict__ lst) {
  int q = blockIdx.x * 256 + threadIdx.x;
  int zbr = blockIdx.y;
  float m0 = pm[(long)zbr * 4096 + q],        l0 = pl[(long)zbr * 4096 + q];
  float m1 = pm[(long)(4 + zbr) * 4096 + q],  l1 = pl[(long)(4 + zbr) * 4096 + q];
  float m = fmaxf(m0, m1);
  float l = l0 * exp2_fast((m0 - m) * LOG2E) + l1 * exp2_fast((m1 - m) * LOG2E);
  mst[(long)zbr * 4096 + q] = m;
  lst[(long)zbr * 4096 + q] = 1.0f / l;
}

// ---------------------------------------------------------------------------
// Fused recompute-S PV, 8-wave blocks (512 thr), qc0 chunk 256 (R2 structure).
// NEW (T14 async-split): next chunk's first-half K fragments (8 x bf16x8,
// 32 VGPR) are loaded at the TOP of the V phase, so the S phase starts with
// its K data in registers; the S-phase second-half K loads issue at S-start
// and are covered by the first-half MFMAs. Pl exchange barriers lgkm-only;
// first 128 V columns prefetched before the P-write barrier.
// LDS = Qres+Pl = 66.6 KB -> 2 blocks/CU.
// ---------------------------------------------------------------------------
__global__ __launch_bounds__(512, 4)
void fused_pv(const __bf16* __restrict__ qs, const __bf16* __restrict__ qc,
              const __bf16* __restrict__ ks, const __bf16* __restrict__ kc,
              const __bf16* __restrict__ vs, const __bf16* __restrict__ vc,
              const float* __restrict__ mst, const float* __restrict__ lst,
              float* __restrict__ gacc)
{
  __shared__ __align__(16) __bf16 Qres[64 * 260];   // 33.3 KB (conflict-free)
  __shared__ __align__(16) __bf16 Pl[64 * 260];     // 33.3 KB (k-chunk 256)

  const int tid = threadIdx.x, lane = tid & 63, w = tid >> 6;   // w in [0,8)
  const int quad = lane >> 4, l15 = lane & 15;
  const int lid = blockIdx.x;
  const int g   = lid & 7;
  const int zbr = g >> 1;
  const int qh  = g & 1;
  const int bi  = (lid >> 3) * 64;
  const int br = zbr >> 1, z = zbr & 1;
  const __bf16* Qt = (br ? qc : qs) + (long)z * 1048576;
  const __bf16* Kt = (br ? kc : ks) + (long)z * 1048576;
  const __bf16* Vv = (br ? vc : vs) + (long)z * 1048576;
  const float* msp = mst + (long)zbr * 4096;
  const float* lsp = lst + (long)zbr * 4096;
  float* go = gacc + ((long)qh * 4 + zbr) * 1048576;

  for (int idx = tid; idx < 2048; idx += 512) {
    int r = idx >> 5, c8 = (idx & 31) * 8;
    *(bf16x8*)(Qres + r * 260 + c8) = *(const bf16x8*)(Qt + (long)(bi + r) * 256 + c8);
  }
  __syncthreads();

  f32x4 accO[4][2] = {};
  const int q0 = qh * 2048;
  // per-lane V row pointers (output channels j = w*32 + nt*16 + l15)
  const __bf16* Vl0 = Vv + (long)(w * 32 + l15) * 4096 + quad * 8;
  const __bf16* Vl1 = Vl0 + (long)16 * 4096;
  // per-lane K row pointers (q rows = w*32 + {l15, 16+l15}), + qc0*256 later
  const __bf16* Kb0 = Kt + (long)(w * 32 + l15) * 256 + quad * 8;
  const __bf16* Kb1 = Kb0 + 16 * 256;

  // prefetch chunk 0's first-half K (cs 0..127)
  bf16x8 kpre[8];
  {
    const __bf16* K0 = Kb0 + (long)q0 * 256;
    const __bf16* K1 = Kb1 + (long)q0 * 256;
#pragma unroll
    for (int h = 0; h < 4; ++h) {
      kpre[2 * h]     = *(const bf16x8*)(K0 + h * 32);
      kpre[2 * h + 1] = *(const bf16x8*)(K1 + h * 32);
    }
  }

  for (int qc0 = q0; qc0 < q0 + 2048; qc0 += 256) {
    // --- S phase: first half from kpre, second half direct (issued early) ---
    f32x4 accS[4][2] = {};
    const __bf16* Kl0 = Kb0 + (long)qc0 * 256;
    const __bf16* Kl1 = Kb1 + (long)qc0 * 256;
#pragma unroll
    for (int cs = 0; cs < 256; cs += 32) {
      bf16x8 aq[4];
      bf16x8 bk0, bk1;
      if (cs < 128) { bk0 = kpre[cs >> 4]; bk1 = kpre[(cs >> 4) + 1]; }
      else {
        bk0 = *(const bf16x8*)(Kl0 + cs);
        bk1 = *(const bf16x8*)(Kl1 + cs);
      }
#pragma unroll
      for (int mt = 0; mt < 4; ++mt)
        aq[mt] = *(const bf16x8*)(Qres + (mt * 16 + l15) * 260 + cs + quad * 8);
      __builtin_amdgcn_s_setprio(1);
#pragma unroll
      for (int mt = 0; mt < 4; ++mt) {
        accS[mt][0] = __builtin_amdgcn_mfma_f32_16x16x32_bf16(aq[mt], bk0, accS[mt][0], 0, 0, 0);
        accS[mt][1] = __builtin_amdgcn_mfma_f32_16x16x32_bf16(aq[mt], bk1, accS[mt][1], 0, 0, 0);
      }
      __builtin_amdgcn_s_setprio(0);
    }
    // prefetch: stats + first 128 V columns of this chunk (consumed after bars)
    float mq0 = msp[qc0 + w * 32 + l15],      lq0 = lsp[qc0 + w * 32 + l15];
    float mq1 = msp[qc0 + w * 32 + 16 + l15], lq1 = lsp[qc0 + w * 32 + 16 + l15];
    bf16x8 pv00 = *(const bf16x8*)(Vl0 + qc0);
    bf16x8 pv01 = *(const bf16x8*)(Vl1 + qc0);
    bf16x8 pv10 = *(const bf16x8*)(Vl0 + qc0 + 32);
    bf16x8 pv11 = *(const bf16x8*)(Vl1 + qc0 + 32);
    bf16x8 pv20 = *(const bf16x8*)(Vl0 + qc0 + 64);
    bf16x8 pv21 = *(const bf16x8*)(Vl1 + qc0 + 64);
    bf16x8 pv30 = *(const bf16x8*)(Vl0 + qc0 + 96);
    bf16x8 pv31 = *(const bf16x8*)(Vl1 + qc0 + 96);
    bar_lgkm();   // all waves' previous V-phase Pl reads complete
    // P = exp(S - m_q)*linv_q -> Pl
#pragma unroll
    for (int nt = 0; nt < 2; ++nt) {
      int q = w * 32 + nt * 16 + l15;
      float mq = nt ? mq1 : mq0, lq = nt ? lq1 : lq0;
#pragma unroll
      for (int mt = 0; mt < 4; ++mt)
#pragma unroll
        for (int r = 0; r < 4; ++r) {
          int i = mt * 16 + quad * 4 + r;
          Pl[i * 260 + q] = (__bf16)(exp2_fast((accS[mt][nt][r] - mq) * LOG2E) * lq);
        }
    }
    bar_lgkm();   // Pl visible to all waves
    // --- issue next chunk's first-half K loads (latency hides under V) ---
    {
      const int qpf = (qc0 + 256 < q0 + 2048) ? qc0 + 256 : q0;
      const __bf16* K0n = Kb0 + (long)qpf * 256;
      const __bf16* K1n = Kb1 + (long)qpf * 256;
#pragma unroll
      for (int h = 0; h < 4; ++h) {
        kpre[2 * h]     = *(const bf16x8*)(K0n + h * 32);
        kpre[2 * h + 1] = *(const bf16x8*)(K1n + h * 32);
      }
    }
    // --- V phase: direct-reg V, no barriers ---
#pragma unroll
    for (int qs0 = 0; qs0 < 256; qs0 += 32) {
      bf16x8 ap[4], bv0, bv1;
      if (qs0 == 0)       { bv0 = pv00; bv1 = pv01; }
      else if (qs0 == 32) { bv0 = pv10; bv1 = pv11; }
      else if (qs0 == 64) { bv0 = pv20; bv1 = pv21; }
      else if (qs0 == 96) { bv0 = pv30; bv1 = pv31; }
      else {
        bv0 = *(const bf16x8*)(Vl0 + qc0 + qs0);
        bv1 = *(const bf16x8*)(Vl1 + qc0 + qs0);
      }
#pragma unroll
      for (int mt = 0; mt < 4; ++mt)
        ap[mt] = *(const bf16x8*)(Pl + (mt * 16 + l15) * 260 + qs0 + quad * 8);
      __builtin_amdgcn_s_setprio(1);
#pragma unroll
      for (int mt = 0; mt < 4; ++mt) {
        accO[mt][0] = __builtin_amdgcn_mfma_f32_16x16x32_bf16(ap[mt], bv0, accO[mt][0], 0, 0, 0);
        accO[mt][1] = __builtin_amdgcn_mfma_f32_16x16x32_bf16(ap[mt], bv1, accO[mt][1], 0, 0, 0);
      }
      __builtin_amdgcn_s_setprio(0);
    }
  }
  // natural-layout fp32 partial store (coalesced 64B segments)
#pragma unroll
  for (int mt = 0; mt < 4; ++mt)
#pragma unroll
    for (int nt = 0; nt < 2; ++nt)
#pragma unroll
      for (int r = 0; r < 4; ++r) {
        int i = mt * 16 + quad * 4 + r;
        int j = w * 32 + nt * 16 + l15;
        go[(long)(bi + i) * 256 + j] = accO[mt][nt][r];
      }
}

// ---------------------------------------------------------------------------
// Sum the two q-half partials and write GTS in raw-reshape layout via LDS
// transpose. grid (jg 4, v 16, zbr 4), 256 threads.
__global__ __launch_bounds__(256)
void gsum_reshape(const float* __restrict__ ga, __bf16* __restrict__ gt) {
  __shared__ __bf16 lds[64 * 260];
  const int t = threadIdx.x, lane = t & 63, w = t >> 6;
  const int zbr = blockIdx.z;
  const int v   = blockIdx.y;
  const int jg  = blockIdx.x;
  const float* g0 = ga + (long)zbr * 1048576;
  const float* g1 = g0 + 4194304;
  for (int ci0 = 0; ci0 < 256; ci0 += 4) {
    int ci = ci0 + w;
    long src = (long)(ci * 16 + v) * 256 + jg * 64 + lane;
    lds[lane * 260 + ci] = (__bf16)(g0[src] + g1[src]);
  }
  __syncthreads();
  __bf16* out = gt + (long)zbr * 1048576 + ((long)v * 256 + jg * 64) * 256;
#pragma unroll
  for (int pp = 0; pp < 8; ++pp) {
    int idx = pp * 256 + t;
    int row = idx >> 5, c8 = (idx & 31) * 8;
    *(bf16x8*)(out + (long)row * 256 + c8) = *(const bf16x8*)(lds + row * 260 + c8);
  }
}

// ---------------------------------------------------------------------------
// Weight fold: WT = [Wfu_l*Wgs | Wfu_v*Wgs | Wfu_l | Wfu_v] (bf16 [256][1024]),
// biasT[co] = bfu[co] + sum_c (Wfu[co][c]+Wfu[co][c+256]) * bgs[c].
// Also zeroes the 256-B zero page used by gemm_conv border lanes.
__global__ __launch_bounds__(256)
void wcomb(const float* __restrict__ Wgs, const float* __restrict__ bgs,
           const float* __restrict__ Wfu, const float* __restrict__ bfu,
           __bf16* __restrict__ WT, float* __restrict__ biasT,
           float* __restrict__ zp)
{
  const int co = blockIdx.x, t = threadIdx.x;
  if (co == 0 && t < 64) zp[t] = 0.f;
  const float* wrow = Wfu + (long)co * 512;
  float accs = 0.f, accc = 0.f;
  for (int c = 0; c < 256; ++c) {
    float gv = Wgs[(long)c * 256 + t];
    accs = fmaf(wrow[c], gv, accs);
    accc = fmaf(wrow[c + 256], gv, accc);
  }
  __bf16* o = WT + (long)co * 1024;
  o[t]       = (__bf16)accs;
  o[256 + t] = (__bf16)accc;
  o[512 + t] = (__bf16)wrow[t];
  o[768 + t] = (__bf16)wrow[256 + t];
  __shared__ float red[256];
  red[t] = (wrow[t] + wrow[t + 256]) * bgs[t];
  __syncthreads();
  for (int s = 128; s > 0; s >>= 1) {
    if (t < s) red[t] += red[t + s];
    __syncthreads();
  }
  if (t == 0) biasT[co] = bfu[co] + red[0];
}

// ---------------------------------------------------------------------------
// Tail GEMM: out[z][co][p] = sum_k WT[co][k] * Bcat[z][p][k] + biasT[co],
// Bcat k-groups: 0 GTS_s, 1 GTS_c, 2 Xt(Fl), 3 Xt(Fv). Swizzled LDS.
__global__ __launch_bounds__(256)
void tail_gemm(const __bf16* __restrict__ WT, const __bf16* __restrict__ GTS,
               const __bf16* __restrict__ Xt, const float* __restrict__ biasT,
               float* __restrict__ out)
{
  __shared__ __align__(16) __bf16 smem[8192];
  __bf16* As = smem;
  __bf16* Bs = smem + 4096;

  const int tid  = threadIdx.x;
  const int lane = tid & 63;
  const int w    = tid >> 6;
  const int wm   = (w >> 1) * 64;
  const int wn   = (w & 1) * 64;
  const int z    = blockIdx.z;
  const int bm   = blockIdx.y * 128;
  const int bn   = blockIdx.x * 128;

  const __bf16* Bsel[4] = {
    GTS + (long)z * 1048576, GTS + (long)(2 + z) * 1048576,
    Xt  + (long)z * 1048576, Xt  + (long)(2 + z) * 1048576
  };

  f32x4 acc[4][4] = {};
  const int srow = lane >> 2;
  const int skc  = SWZ_STAGE(lane);
  const int quad = lane >> 4, l15 = lane & 15;
  const int rdo  = SWZ_READ(quad, lane);

  for (int k0 = 0; k0 < 1024; k0 += 32) {
    const __bf16* Bb = Bsel[k0 >> 8];
    const int kk = k0 & 255;
#pragma unroll
    for (int j = 0; j < 2; ++j) {
      int rbase = w * 32 + j * 16;
      stage16(WT + (long)(bm + rbase + srow) * 1024 + k0 + skc, As + rbase * 32);
    }
#pragma unroll
    for (int j = 0; j < 2; ++j) {
      int rbase = w * 32 + j * 16;
      stage16(Bb + (long)(bn + rbase + srow) * 256 + kk + skc, Bs + rbase * 32);
    }
    __syncthreads();
    bf16x8 af[4], bfr[4];
#pragma unroll
    for (int t = 0; t < 4; ++t)
      af[t] = *(const bf16x8*)(As + (wm + t * 16 + l15) * 32 + rdo);
#pragma unroll
    for (int t = 0; t < 4; ++t)
      bfr[t] = *(const bf16x8*)(Bs + (wn + t * 16 + l15) * 32 + rdo);
#pragma unroll
    for (int mt = 0; mt < 4; ++mt)
#pragma unroll
      for (int nt = 0; nt < 4; ++nt)
        acc[mt][nt] = __builtin_amdgcn_mfma_f32_16x16x32_bf16(af[mt], bfr[nt], acc[mt][nt], 0, 0, 0);
    __syncthreads();
  }

#pragma unroll
  for (int mt = 0; mt < 4; ++mt)
#pragma unroll
    for (int nt = 0; nt < 4; ++nt)
#pragma unroll
      for (int r = 0; r < 4; ++r) {
        int m = bm + wm + mt * 16 + quad * 4 + r;
        int n = bn + wn + nt * 16 + l15;
        out[((long)z * 256 + m) * HWSZ + n] = acc[mt][nt][r] + biasT[m];
      }
}

// ---------------------------------------------------------------------------
// Fl/Fv [b][256][4096] fp32 -> Xt [img][4096][256] bf16 (Fl b0, Fl b1, Fv b0, Fv b1)
__global__ void transpose_cvt(const float* __restrict__ F0, const float* __restrict__ F1,
                              __bf16* __restrict__ Xt) {
  __shared__ float tile[32][33];
  int img = blockIdx.z;
  const float* src = (img < 2 ? F0 : F1) + (long)(img & 1) * (CCH * HWSZ);
  __bf16* dst = Xt + (long)img * (HWSZ * CCH);
  int p0 = blockIdx.x * 32, c0 = blockIdx.y * 32;
  int tx = threadIdx.x, ty = threadIdx.y;
#pragma unroll
  for (int j = 0; j < 32; j += 8)
    tile[ty + j][tx] = src[(long)(c0 + ty + j) * HWSZ + p0 + tx];
  __syncthreads();
#pragma unroll
  for (int j = 0; j < 32; j += 8)
    dst[(long)(p0 + ty + j) * CCH + c0 + tx] = (__bf16)tile[tx][ty + j];
}

// W[co][ci][3][3] fp32 -> A[co][t*256+ci] bf16, stacked AL (Wqs,Wks,Wvs,Wqc), AV (Wkc,Wvc)
struct W6 { const float* w[6]; };
__global__ void repack_w3(W6 wp, __bf16* __restrict__ AL, __bf16* __restrict__ AV) {
  int zi = blockIdx.y;
  int e = blockIdx.x * 256 + threadIdx.x;
  int co = e / 2304;
  int rem = e - co * 2304;
  int t = rem >> 8, ci = rem & 255;
  float v = wp.w[zi][(long)co * 2304 + ci * 9 + t];
  __bf16* dst = (zi < 4) ? (AL + (long)zi * 256 * 2304) : (AV + (long)(zi - 4) * 256 * 2304);
  dst[(long)co * 2304 + rem] = (__bf16)v;
}

// ---------------------------------------------------------------------------
extern "C" void kernel_launch(void* const* d_in, const int* in_sizes, int n_in,
                              void* d_out, int out_size, void* d_ws, size_t ws_size,
                              hipStream_t stream) {
  const float* Fl  = (const float*)d_in[0];
  const float* Fv  = (const float*)d_in[1];
  const float* Wqs = (const float*)d_in[2];  const float* bqs = (const float*)d_in[3];
  const float* Wks = (const float*)d_in[4];  const float* bks = (const float*)d_in[5];
  const float* Wvs = (const float*)d_in[6];  const float* bvs = (const float*)d_in[7];
  const float* Wqc = (const float*)d_in[8];  const float* bqc = (const float*)d_in[9];
  const float* Wkc = (const float*)d_in[10]; const float* bkc = (const float*)d_in[11];
  const float* Wvc = (const float*)d_in[12]; const float* bvc = (const float*)d_in[13];
  const float* Wgs = (const float*)d_in[14]; const float* bgs = (const float*)d_in[15];
  const float* Wfu = (const float*)d_in[16]; const float* bfu = (const float*)d_in[17];

  char* ws = (char*)d_ws;
  size_t off = 0;
  auto take = [&](size_t bytes) -> void* {
    void* p = ws + off; off = (off + bytes + 255) & ~(size_t)255; return p;
  };
  __bf16* QST  = (__bf16*)take(4194304);   // Qs^T  [b][4096][256]
  __bf16* KST  = (__bf16*)take(4194304);
  __bf16* QCT  = (__bf16*)take(4194304);
  __bf16* KCT  = (__bf16*)take(4194304);
  __bf16* VS   = (__bf16*)take(4194304);   // Vs    [b][256][4096]
  __bf16* VC   = (__bf16*)take(4194304);
  __bf16* GTS  = (__bf16*)take(8388608);   // G (reshape layout) [br*2+z][4096][256]
  __bf16* AL   = (__bf16*)take(4718592);   // conv weights [1024][2304]
  __bf16* AV   = (__bf16*)take(2359296);   // [512][2304]
  __bf16* WT   = (__bf16*)take(524288);    // folded tail weights [256][1024]
  float*  BT   = (float*)take(1024);       // folded tail bias [256]
  float*  ZP   = (float*)take(256);        // zero page for conv border lanes
  float*  MST  = (float*)take(65536);      // [br*2+z][4096]
  float*  LST  = (float*)take(65536);
  float*  PM   = (float*)take(131072);     // partial stats [ih][zbr][4096]
  float*  PL   = (float*)take(131072);
  __bf16* Xt   = (__bf16*)take(8388608);   // [img][4096][256] — alive through tail
  size_t ovl = off;                        // GACC after all persistent buffers
  float* GACC = (float*)(ws + ovl);        // [2 qh][4 zbr][4096*256] fp32 = 32 MB
  size_t need = ovl + 33554432;
  if (ws_size < need) return;

  transpose_cvt<<<dim3(128, 8, 4), dim3(32, 8), 0, stream>>>(Fl, Fv, Xt);
  W6 wp; wp.w[0]=Wqs; wp.w[1]=Wks; wp.w[2]=Wvs; wp.w[3]=Wqc; wp.w[4]=Wkc; wp.w[5]=Wvc;
  repack_w3<<<dim3(2304, 6), 256, 0, stream>>>(wp, AL, AV);
  wcomb<<<dim3(256), 256, 0, stream>>>(Wgs, bgs, Wfu, bfu, WT, BT, ZP);

  gemm_conv<<<dim3(32, 12, 2), 256, 0, stream>>>(
      AL, AV, Xt, (const __bf16*)ZP, QST, KST, VS, QCT, KCT, VC,
      bqs, bks, bvs, bqc, bkc, bvc);

  qk_stats<<<dim3(512), 256, 0, stream>>>(QST, QCT, KST, KCT, PM, PL);
  stats_combine2<<<dim3(16, 4), 256, 0, stream>>>(PM, PL, MST, LST);

  fused_pv<<<dim3(512), 512, 0, stream>>>(
      QST, QCT, KST, KCT, VS, VC, MST, LST, GACC);

  gsum_reshape<<<dim3(4, 16, 4), 256, 0, stream>>>(GACC, GTS);

  tail_gemm<<<dim3(32, 2, 2), 256, 0, stream>>>(WT, GTS, Xt, BT, (float*)d_out);
}

// Round 9
// 439.682 us; speedup vs baseline: 1.0405x; 1.0405x over previous
//
#include <hip/hip_runtime.h>

typedef __bf16 bf16x4 __attribute__((ext_vector_type(4)));
typedef __bf16 bf16x8 __attribute__((ext_vector_type(8)));
typedef float  f32x4  __attribute__((ext_vector_type(4)));

#define HWSZ 4096
#define CCH  256
#define LOG2E 1.44269504088896340736f

__device__ __forceinline__ float exp2_fast(float x) {
#if __has_builtin(__builtin_amdgcn_exp2f)
  return __builtin_amdgcn_exp2f(x);
#else
  return exp2f(x);
#endif
}

// barrier that only drains LDS ops (lgkmcnt), letting global loads stay in
// flight across the barrier. Safe when the barrier only protects LDS state.
__device__ __forceinline__ void bar_lgkm() {
  asm volatile("s_waitcnt lgkmcnt(0)" ::: "memory");
  __builtin_amdgcn_s_barrier();
}

// stage 16B per lane into LDS; lane's data lands at lds_base + lane*16B
__device__ __forceinline__ void stage16(const __bf16* g, __bf16* ldsBase) {
#if __has_builtin(__builtin_amdgcn_global_load_lds)
  __builtin_amdgcn_global_load_lds(
      (const __attribute__((address_space(1))) void*)g,
      (__attribute__((address_space(3))) void*)ldsBase, 16, 0, 0);
#else
  int lane = threadIdx.x & 63;
  *(bf16x8*)(ldsBase + lane * 8) = *(const bf16x8*)g;
#endif
}

// XOR swizzle for 32-elem-row LDS tiles: phys 16B-chunk = logical ^ ((row>>1)&3).
#define SWZ_STAGE(lane) ((((lane) & 3) ^ (((lane) >> 3) & 3)) * 8)
#define SWZ_READ(quad, lane) ((((quad) ^ (((lane) >> 1) & 3))) * 8)

// ---------------------------------------------------------------------------
// Merged conv3x3 GEMM, implicit-im2col, 2-PHASE double-buffered (T3 minimum):
// tile t+1's global_load_lds issued BEFORE tile t's MFMAs (loads fly under
// compute); ONE vmcnt(0)+barrier per k-step (was 2 barriers + serial load
// latency). by<8 -> A=AL (Qs,Ks,Vs,Qc from Fl), else A=AV (Kc,Vc from Fv).
// B staged directly from Xt [img][4096][256]: tap t=k0>>8 (dy,dx), border
// lanes read a zero page. LDS 32 KB (2 x (As 8K + Bs 8K)).
// ---------------------------------------------------------------------------
__global__ __launch_bounds__(256)
void gemm_conv(const __bf16* __restrict__ AL, const __bf16* __restrict__ AV,
               const __bf16* __restrict__ Xt, const __bf16* __restrict__ zp,
               __bf16* __restrict__ qst, __bf16* __restrict__ kst,
               __bf16* __restrict__ vs,  __bf16* __restrict__ qct,
               __bf16* __restrict__ kct, __bf16* __restrict__ vc,
               const float* __restrict__ bqs, const float* __restrict__ bks,
               const float* __restrict__ bvs, const float* __restrict__ bqc,
               const float* __restrict__ bkc, const float* __restrict__ bvc)
{
  __shared__ __align__(16) __bf16 smem[16384];   // 2 bufs x (As 4096 + Bs 4096)

  const int tid  = threadIdx.x;
  const int lane = tid & 63;
  const int w    = tid >> 6;
  const int wm   = (w >> 1) * 64;
  const int wn   = (w & 1) * 64;
  const int z    = blockIdx.z;
  const int by   = blockIdx.y;
  const int bn   = blockIdx.x * 128;
  const int K    = 2304;

  const bool isL = (by < 8);
  const int bm = (isL ? by : by - 8) * 128;
  const __bf16* Ab = isL ? AL : AV;
  const __bf16* Xb = Xt + (long)((isL ? 0 : 2) + z) * (HWSZ * CCH);

  f32x4 acc[4][4] = {};
  const int srow = lane >> 2;
  const int skc  = SWZ_STAGE(lane);
  const int quad = lane >> 4, l15 = lane & 15;
  const int rdo  = SWZ_READ(quad, lane);

  // stage tile (k0) into buffer base
  auto stage_tile = [&](int k0, __bf16* As, __bf16* Bs) {
    const int t9  = k0 >> 8;                 // tap 0..8 (uniform per k0)
    const int dy  = t9 / 3 - 1;
    const int dx  = t9 - (t9 / 3) * 3 - 1;
    const int off = dy * 64 + dx;
    const int ci0 = k0 & 255;
#pragma unroll
    for (int j = 0; j < 2; ++j) {
      int rbase = w * 32 + j * 16;
      stage16(Ab + (long)(bm + rbase + srow) * K + k0 + skc, As + rbase * 32);
    }
#pragma unroll
    for (int j = 0; j < 2; ++j) {
      int rbase = w * 32 + j * 16;
      int p = bn + rbase + srow;
      int y = p >> 6, x = p & 63;
      bool valid = ((unsigned)(y + dy) < 64u) && ((unsigned)(x + dx) < 64u);
      const __bf16* src = valid ? (Xb + (long)(p + off) * CCH + ci0 + skc) : zp;
      stage16(src, Bs + rbase * 32);
    }
  };

  // prologue: stage tile 0 into buf0
  stage_tile(0, smem, smem + 4096);
  asm volatile("s_waitcnt vmcnt(0)" ::: "memory");
  __builtin_amdgcn_s_barrier();

  for (int k0 = 0; k0 < K; k0 += 32) {
    const int cur = (k0 >> 5) & 1;
    __bf16* As = smem + cur * 8192;
    __bf16* Bs = As + 4096;
    // issue next tile's loads first — they fly under this tile's MFMAs
    const int nxt = k0 + 32;
    if (nxt < K) {
      __bf16* An = smem + (cur ^ 1) * 8192;
      stage_tile(nxt, An, An + 4096);
    }
    bf16x8 af[4], bfr[4];
#pragma unroll
    for (int t = 0; t < 4; ++t)
      af[t] = *(const bf16x8*)(As + (wm + t * 16 + l15) * 32 + rdo);
#pragma unroll
    for (int t = 0; t < 4; ++t)
      bfr[t] = *(const bf16x8*)(Bs + (wn + t * 16 + l15) * 32 + rdo);
    __builtin_amdgcn_s_setprio(1);
#pragma unroll
    for (int mt = 0; mt < 4; ++mt)
#pragma unroll
      for (int nt = 0; nt < 4; ++nt)
        acc[mt][nt] = __builtin_amdgcn_mfma_f32_16x16x32_bf16(af[mt], bfr[nt], acc[mt][nt], 0, 0, 0);
    __builtin_amdgcn_s_setprio(0);
    // next tile's loads landed (mine) + my LDS reads done; one barrier/iter
    asm volatile("s_waitcnt vmcnt(0) lgkmcnt(0)" ::: "memory");
    __builtin_amdgcn_s_barrier();
  }

#pragma unroll
  for (int mt = 0; mt < 4; ++mt) {
#pragma unroll
    for (int nt = 0; nt < 4; ++nt) {
#pragma unroll
      for (int r = 0; r < 4; ++r) {
        int m = bm + wm + mt * 16 + quad * 4 + r;
        int n = bn + wn + nt * 16 + l15;
        int g = m >> 8, mm = m & 255;
        const float* bias; __bf16* op; bool vlay;
        if (isL) {
          bias = (g == 0) ? bqs : (g == 1) ? bks : (g == 2) ? bvs : bqc;
          op   = (g == 0) ? qst : (g == 1) ? kst : (g == 2) ? vs  : qct;
          vlay = (g == 2);
        } else {
          bias = g ? bvc : bkc;
          op   = g ? vc  : kct;
          vlay = (g == 1);
        }
        float vv = acc[mt][nt][r] + bias[mm];
        if (vlay) op[(long)z * 1048576 + (long)mm * HWSZ + n] = (__bf16)vv;   // V: [c,p]
        else      op[(long)z * 1048576 + (long)n * CCH + mm] = (__bf16)vv;    // Q/K: [p,c]
      }
    }
  }
}

// ---------------------------------------------------------------------------
// qk_stats: partial column-softmax stats over HALF the i-range.
// 1-D grid 512: lid -> (g: z,br | ih | qb). Kres stride 260 (conflict-free).
// ---------------------------------------------------------------------------
__global__ __launch_bounds__(256)
void qk_stats(const __bf16* __restrict__ qs, const __bf16* __restrict__ qc,
              const __bf16* __restrict__ ks, const __bf16* __restrict__ kc,
              float* __restrict__ pm, float* __restrict__ pl)
{
  __shared__ __align__(16) __bf16 Kres[64 * 260];
  __shared__ float wm_[4][64], wl_[4][64];

  const int tid = threadIdx.x, lane = tid & 63, w = tid >> 6;
  const int quad = lane >> 4, l15 = lane & 15;
  const int lid = blockIdx.x;
  const int g = lid & 3;
  const int z = g & 1, br = g >> 1;
  const int ih = (lid >> 2) & 1;
  const int qb = (lid >> 3) * 64;
  const __bf16* Qt = (br ? qc : qs) + (long)z * 1048576;
  const __bf16* Kt = (br ? kc : ks) + (long)z * 1048576;

  for (int idx = tid; idx < 2048; idx += 256) {
    int r = idx >> 5, c8 = (idx & 31) * 8;
    *(bf16x8*)(Kres + r * 260 + c8) = *(const bf16x8*)(Kt + (long)(qb + r) * 256 + c8);
  }
  __syncthreads();

  float rm[4], rl[4];
#pragma unroll
  for (int nt = 0; nt < 4; ++nt) { rm[nt] = -3.0e38f; rl[nt] = 0.f; }

  for (int it = 0; it < 8; ++it) {
    const int i0 = ih * 2048 + it * 256 + w * 64;
    f32x4 accS[4][4] = {};
#pragma unroll
    for (int cs = 0; cs < 256; cs += 32) {
      bf16x8 a[4], b[4];
#pragma unroll
      for (int mt = 0; mt < 4; ++mt)
        a[mt] = *(const bf16x8*)(Qt + (long)(i0 + mt * 16 + l15) * 256 + cs + quad * 8);
#pragma unroll
      for (int nt = 0; nt < 4; ++nt)
        b[nt] = *(const bf16x8*)(Kres + (nt * 16 + l15) * 260 + cs + quad * 8);
      __builtin_amdgcn_s_setprio(1);
#pragma unroll
      for (int mt = 0; mt < 4; ++mt)
#pragma unroll
        for (int nt = 0; nt < 4; ++nt)
          accS[mt][nt] = __builtin_amdgcn_mfma_f32_16x16x32_bf16(a[mt], b[nt], accS[mt][nt], 0, 0, 0);
      __builtin_amdgcn_s_setprio(0);
    }
#pragma unroll
    for (int nt = 0; nt < 4; ++nt) {
      float mx = -3.0e38f;
#pragma unroll
      for (int mt = 0; mt < 4; ++mt)
#pragma unroll
        for (int r = 0; r < 4; ++r) mx = fmaxf(mx, accS[mt][nt][r]);
      float sl = 0.f;
#pragma unroll
      for (int mt = 0; mt < 4; ++mt)
#pragma unroll
        for (int r = 0; r < 4; ++r) sl += exp2_fast((accS[mt][nt][r] - mx) * LOG2E);
#pragma unroll
      for (int d = 16; d <= 32; d <<= 1) {
        float om = __shfl_xor(mx, d, 64);
        float ol = __shfl_xor(sl, d, 64);
        float nm = fmaxf(mx, om);
        sl = sl * exp2_fast((mx - nm) * LOG2E) + ol * exp2_fast((om - nm) * LOG2E);
        mx = nm;
      }
      float nm = fmaxf(rm[nt], mx);
      rl[nt] = rl[nt] * exp2_fast((rm[nt] - nm) * LOG2E) + sl * exp2_fast((mx - nm) * LOG2E);
      rm[nt] = nm;
    }
  }
  if (lane < 16) {
#pragma unroll
    for (int nt = 0; nt < 4; ++nt) { wm_[w][nt * 16 + lane] = rm[nt]; wl_[w][nt * 16 + lane] = rl[nt]; }
  }
  __syncthreads();
  if (tid < 64) {
    float m = -3.0e38f;
#pragma unroll
    for (int ww = 0; ww < 4; ++ww) m = fmaxf(m, wm_[ww][tid]);
    float l = 0.f;
#pragma unroll
    for (int ww = 0; ww < 4; ++ww)
      l += wl_[ww][tid] * exp2_fast((wm_[ww][tid] - m) * LOG2E);
    long o = ((long)ih * 4 + br * 2 + z) * 4096 + qb + tid;
    pm[o] = m;
    pl[o] = l;
  }
}

// combine the two i-half partials -> final m, 1/l. grid (16, 4 zbr), 256 thr.
__global__ void stats_combine2(const float* __restrict__ pm, const float* __restrict__ pl,
                               float* __restrict__ mst, float* __restrict__ lst) {
  int q = blockIdx.x * 256 + threadIdx.x;
  int zbr = blockIdx.y;
  float m0 = pm[(long)zbr * 4096 + q],        l0 = pl[(long)zbr * 4096 + q];
  float m1 = pm[(long)(4 + zbr) * 4096 + q],  l1 = pl[(long)(4 + zbr) * 4096 + q];
  float m = fmaxf(m0, m1);
  float l = l0 * exp2_fast((m0 - m) * LOG2E) + l1 * exp2_fast((m1 - m) * LOG2E);
  mst[(long)zbr * 4096 + q] = m;
  lst[(long)zbr * 4096 + q] = 1.0f / l;
}

// ---------------------------------------------------------------------------
// Fused recompute-S PV, 8-wave blocks (512 thr), qc0 chunk 256 — exact R6
// form (best measured 137 us; R8's K-prefetch regressed via scratch spill,
// reverted). K and V direct global->reg (L2-resident via lid&7 XCD pinning).
// Pl exchange barriers lgkm-only; first 128 V columns prefetched before the
// P-write barrier. LDS = Qres+Pl = 66.6 KB -> 2 blocks/CU.
// ---------------------------------------------------------------------------
__global__ __launch_bounds__(512, 4)
void fused_pv(const __bf16* __restrict__ qs, const __bf16* __restrict__ qc,
              const __bf16* __restrict__ ks, const __bf16* __restrict__ kc,
              const __bf16* __restrict__ vs, const __bf16* __restrict__ vc,
              const float* __restrict__ mst, const float* __restrict__ lst,
              float* __restrict__ gacc)
{
  __shared__ __align__(16) __bf16 Qres[64 * 260];   // 33.3 KB (conflict-free)
  __shared__ __align__(16) __bf16 Pl[64 * 260];     // 33.3 KB (k-chunk 256)

  const int tid = threadIdx.x, lane = tid & 63, w = tid >> 6;   // w in [0,8)
  const int quad = lane >> 4, l15 = lane & 15;
  const int lid = blockIdx.x;
  const int g   = lid & 7;
  const int zbr = g >> 1;
  const int qh  = g & 1;
  const int bi  = (lid >> 3) * 64;
  const int br = zbr >> 1, z = zbr & 1;
  const __bf16* Qt = (br ? qc : qs) + (long)z * 1048576;
  const __bf16* Kt = (br ? kc : ks) + (long)z * 1048576;
  const __bf16* Vv = (br ? vc : vs) + (long)z * 1048576;
  const float* msp = mst + (long)zbr * 4096;
  const float* lsp = lst + (long)zbr * 4096;
  float* go = gacc + ((long)qh * 4 + zbr) * 1048576;

  for (int idx = tid; idx < 2048; idx += 512) {
    int r = idx >> 5, c8 = (idx & 31) * 8;
    *(bf16x8*)(Qres + r * 260 + c8) = *(const bf16x8*)(Qt + (long)(bi + r) * 256 + c8);
  }
  __syncthreads();

  f32x4 accO[4][2] = {};
  const int q0 = qh * 2048;
  // per-lane V row pointers (output channels j = w*32 + nt*16 + l15)
  const __bf16* Vl0 = Vv + (long)(w * 32 + l15) * 4096 + quad * 8;
  const __bf16* Vl1 = Vl0 + (long)16 * 4096;

  for (int qc0 = q0; qc0 < q0 + 2048; qc0 += 256) {
    // --- S phase: K direct global->reg, wave k-slice 32 ---
    f32x4 accS[4][2] = {};
    const __bf16* Kl0 = Kt + (long)(qc0 + w * 32 + l15) * 256 + quad * 8;
    const __bf16* Kl1 = Kl0 + (long)16 * 256;
#pragma unroll
    for (int cs = 0; cs < 256; cs += 32) {
      bf16x8 aq[4];
      bf16x8 bk0 = *(const bf16x8*)(Kl0 + cs);
      bf16x8 bk1 = *(const bf16x8*)(Kl1 + cs);
#pragma unroll
      for (int mt = 0; mt < 4; ++mt)
        aq[mt] = *(const bf16x8*)(Qres + (mt * 16 + l15) * 260 + cs + quad * 8);
      __builtin_amdgcn_s_setprio(1);
#pragma unroll
      for (int mt = 0; mt < 4; ++mt) {
        accS[mt][0] = __builtin_amdgcn_mfma_f32_16x16x32_bf16(aq[mt], bk0, accS[mt][0], 0, 0, 0);
        accS[mt][1] = __builtin_amdgcn_mfma_f32_16x16x32_bf16(aq[mt], bk1, accS[mt][1], 0, 0, 0);
      }
      __builtin_amdgcn_s_setprio(0);
    }
    // prefetch: stats + first 128 V columns of this chunk (consumed after bars)
    float mq0 = msp[qc0 + w * 32 + l15],      lq0 = lsp[qc0 + w * 32 + l15];
    float mq1 = msp[qc0 + w * 32 + 16 + l15], lq1 = lsp[qc0 + w * 32 + 16 + l15];
    bf16x8 pv00 = *(const bf16x8*)(Vl0 + qc0);
    bf16x8 pv01 = *(const bf16x8*)(Vl1 + qc0);
    bf16x8 pv10 = *(const bf16x8*)(Vl0 + qc0 + 32);
    bf16x8 pv11 = *(const bf16x8*)(Vl1 + qc0 + 32);
    bf16x8 pv20 = *(const bf16x8*)(Vl0 + qc0 + 64);
    bf16x8 pv21 = *(const bf16x8*)(Vl1 + qc0 + 64);
    bf16x8 pv30 = *(const bf16x8*)(Vl0 + qc0 + 96);
    bf16x8 pv31 = *(const bf16x8*)(Vl1 + qc0 + 96);
    bar_lgkm();   // all waves' previous V-phase Pl reads complete
    // P = exp(S - m_q)*linv_q -> Pl
#pragma unroll
    for (int nt = 0; nt < 2; ++nt) {
      int q = w * 32 + nt * 16 + l15;
      float mq = nt ? mq1 : mq0, lq = nt ? lq1 : lq0;
#pragma unroll
      for (int mt = 0; mt < 4; ++mt)
#pragma unroll
        for (int r = 0; r < 4; ++r) {
          int i = mt * 16 + quad * 4 + r;
          Pl[i * 260 + q] = (__bf16)(exp2_fast((accS[mt][nt][r] - mq) * LOG2E) * lq);
        }
    }
    bar_lgkm();   // Pl visible to all waves
    // --- V phase: direct-reg V, no barriers ---
#pragma unroll
    for (int qs0 = 0; qs0 < 256; qs0 += 32) {
      bf16x8 ap[4], bv0, bv1;
      if (qs0 == 0)       { bv0 = pv00; bv1 = pv01; }
      else if (qs0 == 32) { bv0 = pv10; bv1 = pv11; }
      else if (qs0 == 64) { bv0 = pv20; bv1 = pv21; }
      else if (qs0 == 96) { bv0 = pv30; bv1 = pv31; }
      else {
        bv0 = *(const bf16x8*)(Vl0 + qc0 + qs0);
        bv1 = *(const bf16x8*)(Vl1 + qc0 + qs0);
      }
#pragma unroll
      for (int mt = 0; mt < 4; ++mt)
        ap[mt] = *(const bf16x8*)(Pl + (mt * 16 + l15) * 260 + qs0 + quad * 8);
      __builtin_amdgcn_s_setprio(1);
#pragma unroll
      for (int mt = 0; mt < 4; ++mt) {
        accO[mt][0] = __builtin_amdgcn_mfma_f32_16x16x32_bf16(ap[mt], bv0, accO[mt][0], 0, 0, 0);
        accO[mt][1] = __builtin_amdgcn_mfma_f32_16x16x32_bf16(ap[mt], bv1, accO[mt][1], 0, 0, 0);
      }
      __builtin_amdgcn_s_setprio(0);
    }
  }
  // natural-layout fp32 partial store (coalesced 64B segments)
#pragma unroll
  for (int mt = 0; mt < 4; ++mt)
#pragma unroll
    for (int nt = 0; nt < 2; ++nt)
#pragma unroll
      for (int r = 0; r < 4; ++r) {
        int i = mt * 16 + quad * 4 + r;
        int j = w * 32 + nt * 16 + l15;
        go[(long)(bi + i) * 256 + j] = accO[mt][nt][r];
      }
}

// ---------------------------------------------------------------------------
// Sum the two q-half partials and write GTS in raw-reshape layout via LDS
// transpose. grid (jg 4, v 16, zbr 4), 256 threads.
__global__ __launch_bounds__(256)
void gsum_reshape(const float* __restrict__ ga, __bf16* __restrict__ gt) {
  __shared__ __bf16 lds[64 * 260];
  const int t = threadIdx.x, lane = t & 63, w = t >> 6;
  const int zbr = blockIdx.z;
  const int v   = blockIdx.y;
  const int jg  = blockIdx.x;
  const float* g0 = ga + (long)zbr * 1048576;
  const float* g1 = g0 + 4194304;
  for (int ci0 = 0; ci0 < 256; ci0 += 4) {
    int ci = ci0 + w;
    long src = (long)(ci * 16 + v) * 256 + jg * 64 + lane;
    lds[lane * 260 + ci] = (__bf16)(g0[src] + g1[src]);
  }
  __syncthreads();
  __bf16* out = gt + (long)zbr * 1048576 + ((long)v * 256 + jg * 64) * 256;
#pragma unroll
  for (int pp = 0; pp < 8; ++pp) {
    int idx = pp * 256 + t;
    int row = idx >> 5, c8 = (idx & 31) * 8;
    *(bf16x8*)(out + (long)row * 256 + c8) = *(const bf16x8*)(lds + row * 260 + c8);
  }
}

// ---------------------------------------------------------------------------
// Weight fold: WT = [Wfu_l*Wgs | Wfu_v*Wgs | Wfu_l | Wfu_v] (bf16 [256][1024]),
// biasT[co] = bfu[co] + sum_c (Wfu[co][c]+Wfu[co][c+256]) * bgs[c].
// Also zeroes the 256-B zero page used by gemm_conv border lanes.
__global__ __launch_bounds__(256)
void wcomb(const float* __restrict__ Wgs, const float* __restrict__ bgs,
           const float* __restrict__ Wfu, const float* __restrict__ bfu,
           __bf16* __restrict__ WT, float* __restrict__ biasT,
           float* __restrict__ zp)
{
  const int co = blockIdx.x, t = threadIdx.x;
  if (co == 0 && t < 64) zp[t] = 0.f;
  const float* wrow = Wfu + (long)co * 512;
  float accs = 0.f, accc = 0.f;
  for (int c = 0; c < 256; ++c) {
    float gv = Wgs[(long)c * 256 + t];
    accs = fmaf(wrow[c], gv, accs);
    accc = fmaf(wrow[c + 256], gv, accc);
  }
  __bf16* o = WT + (long)co * 1024;
  o[t]       = (__bf16)accs;
  o[256 + t] = (__bf16)accc;
  o[512 + t] = (__bf16)wrow[t];
  o[768 + t] = (__bf16)wrow[256 + t];
  __shared__ float red[256];
  red[t] = (wrow[t] + wrow[t + 256]) * bgs[t];
  __syncthreads();
  for (int s = 128; s > 0; s >>= 1) {
    if (t < s) red[t] += red[t + s];
    __syncthreads();
  }
  if (t == 0) biasT[co] = bfu[co] + red[0];
}

// ---------------------------------------------------------------------------
// Tail GEMM: out[z][co][p] = sum_k WT[co][k] * Bcat[z][p][k] + biasT[co],
// Bcat k-groups: 0 GTS_s, 1 GTS_c, 2 Xt(Fl), 3 Xt(Fv). Swizzled LDS.
__global__ __launch_bounds__(256)
void tail_gemm(const __bf16* __restrict__ WT, const __bf16* __restrict__ GTS,
               const __bf16* __restrict__ Xt, const float* __restrict__ biasT,
               float* __restrict__ out)
{
  __shared__ __align__(16) __bf16 smem[8192];
  __bf16* As = smem;
  __bf16* Bs = smem + 4096;

  const int tid  = threadIdx.x;
  const int lane = tid & 63;
  const int w    = tid >> 6;
  const int wm   = (w >> 1) * 64;
  const int wn   = (w & 1) * 64;
  const int z    = blockIdx.z;
  const int bm   = blockIdx.y * 128;
  const int bn   = blockIdx.x * 128;

  const __bf16* Bsel[4] = {
    GTS + (long)z * 1048576, GTS + (long)(2 + z) * 1048576,
    Xt  + (long)z * 1048576, Xt  + (long)(2 + z) * 1048576
  };

  f32x4 acc[4][4] = {};
  const int srow = lane >> 2;
  const int skc  = SWZ_STAGE(lane);
  const int quad = lane >> 4, l15 = lane & 15;
  const int rdo  = SWZ_READ(quad, lane);

  for (int k0 = 0; k0 < 1024; k0 += 32) {
    const __bf16* Bb = Bsel[k0 >> 8];
    const int kk = k0 & 255;
#pragma unroll
    for (int j = 0; j < 2; ++j) {
      int rbase = w * 32 + j * 16;
      stage16(WT + (long)(bm + rbase + srow) * 1024 + k0 + skc, As + rbase * 32);
    }
#pragma unroll
    for (int j = 0; j < 2; ++j) {
      int rbase = w * 32 + j * 16;
      stage16(Bb + (long)(bn + rbase + srow) * 256 + kk + skc, Bs + rbase * 32);
    }
    __syncthreads();
    bf16x8 af[4], bfr[4];
#pragma unroll
    for (int t = 0; t < 4; ++t)
      af[t] = *(const bf16x8*)(As + (wm + t * 16 + l15) * 32 + rdo);
#pragma unroll
    for (int t = 0; t < 4; ++t)
      bfr[t] = *(const bf16x8*)(Bs + (wn + t * 16 + l15) * 32 + rdo);
#pragma unroll
    for (int mt = 0; mt < 4; ++mt)
#pragma unroll
      for (int nt = 0; nt < 4; ++nt)
        acc[mt][nt] = __builtin_amdgcn_mfma_f32_16x16x32_bf16(af[mt], bfr[nt], acc[mt][nt], 0, 0, 0);
    __syncthreads();
  }

#pragma unroll
  for (int mt = 0; mt < 4; ++mt)
#pragma unroll
    for (int nt = 0; nt < 4; ++nt)
#pragma unroll
      for (int r = 0; r < 4; ++r) {
        int m = bm + wm + mt * 16 + quad * 4 + r;
        int n = bn + wn + nt * 16 + l15;
        out[((long)z * 256 + m) * HWSZ + n] = acc[mt][nt][r] + biasT[m];
      }
}

// ---------------------------------------------------------------------------
// Fl/Fv [b][256][4096] fp32 -> Xt [img][4096][256] bf16 (Fl b0, Fl b1, Fv b0, Fv b1)
__global__ void transpose_cvt(const float* __restrict__ F0, const float* __restrict__ F1,
                              __bf16* __restrict__ Xt) {
  __shared__ float tile[32][33];
  int img = blockIdx.z;
  const float* src = (img < 2 ? F0 : F1) + (long)(img & 1) * (CCH * HWSZ);
  __bf16* dst = Xt + (long)img * (HWSZ * CCH);
  int p0 = blockIdx.x * 32, c0 = blockIdx.y * 32;
  int tx = threadIdx.x, ty = threadIdx.y;
#pragma unroll
  for (int j = 0; j < 32; j += 8)
    tile[ty + j][tx] = src[(long)(c0 + ty + j) * HWSZ + p0 + tx];
  __syncthreads();
#pragma unroll
  for (int j = 0; j < 32; j += 8)
    dst[(long)(p0 + ty + j) * CCH + c0 + tx] = (__bf16)tile[tx][ty + j];
}

// W[co][ci][3][3] fp32 -> A[co][t*256+ci] bf16, stacked AL (Wqs,Wks,Wvs,Wqc), AV (Wkc,Wvc)
struct W6 { const float* w[6]; };
__global__ void repack_w3(W6 wp, __bf16* __restrict__ AL, __bf16* __restrict__ AV) {
  int zi = blockIdx.y;
  int e = blockIdx.x * 256 + threadIdx.x;
  int co = e / 2304;
  int rem = e - co * 2304;
  int t = rem >> 8, ci = rem & 255;
  float v = wp.w[zi][(long)co * 2304 + ci * 9 + t];
  __bf16* dst = (zi < 4) ? (AL + (long)zi * 256 * 2304) : (AV + (long)(zi - 4) * 256 * 2304);
  dst[(long)co * 2304 + rem] = (__bf16)v;
}

// ---------------------------------------------------------------------------
extern "C" void kernel_launch(void* const* d_in, const int* in_sizes, int n_in,
                              void* d_out, int out_size, void* d_ws, size_t ws_size,
                              hipStream_t stream) {
  const float* Fl  = (const float*)d_in[0];
  const float* Fv  = (const float*)d_in[1];
  const float* Wqs = (const float*)d_in[2];  const float* bqs = (const float*)d_in[3];
  const float* Wks = (const float*)d_in[4];  const float* bks = (const float*)d_in[5];
  const float* Wvs = (const float*)d_in[6];  const float* bvs = (const float*)d_in[7];
  const float* Wqc = (const float*)d_in[8];  const float* bqc = (const float*)d_in[9];
  const float* Wkc = (const float*)d_in[10]; const float* bkc = (const float*)d_in[11];
  const float* Wvc = (const float*)d_in[12]; const float* bvc = (const float*)d_in[13];
  const float* Wgs = (const float*)d_in[14]; const float* bgs = (const float*)d_in[15];
  const float* Wfu = (const float*)d_in[16]; const float* bfu = (const float*)d_in[17];

  char* ws = (char*)d_ws;
  size_t off = 0;
  auto take = [&](size_t bytes) -> void* {
    void* p = ws + off; off = (off + bytes + 255) & ~(size_t)255; return p;
  };
  __bf16* QST  = (__bf16*)take(4194304);   // Qs^T  [b][4096][256]
  __bf16* KST  = (__bf16*)take(4194304);
  __bf16* QCT  = (__bf16*)take(4194304);
  __bf16* KCT  = (__bf16*)take(4194304);
  __bf16* VS   = (__bf16*)take(4194304);   // Vs    [b][256][4096]
  __bf16* VC   = (__bf16*)take(4194304);
  __bf16* GTS  = (__bf16*)take(8388608);   // G (reshape layout) [br*2+z][4096][256]
  __bf16* AL   = (__bf16*)take(4718592);   // conv weights [1024][2304]
  __bf16* AV   = (__bf16*)take(2359296);   // [512][2304]
  __bf16* WT   = (__bf16*)take(524288);    // folded tail weights [256][1024]
  float*  BT   = (float*)take(1024);       // folded tail bias [256]
  float*  ZP   = (float*)take(256);        // zero page for conv border lanes
  float*  MST  = (float*)take(65536);      // [br*2+z][4096]
  float*  LST  = (float*)take(65536);
  float*  PM   = (float*)take(131072);     // partial stats [ih][zbr][4096]
  float*  PL   = (float*)take(131072);
  __bf16* Xt   = (__bf16*)take(8388608);   // [img][4096][256] — alive through tail
  size_t ovl = off;                        // GACC after all persistent buffers
  float* GACC = (float*)(ws + ovl);        // [2 qh][4 zbr][4096*256] fp32 = 32 MB
  size_t need = ovl + 33554432;
  if (ws_size < need) return;

  transpose_cvt<<<dim3(128, 8, 4), dim3(32, 8), 0, stream>>>(Fl, Fv, Xt);
  W6 wp; wp.w[0]=Wqs; wp.w[1]=Wks; wp.w[2]=Wvs; wp.w[3]=Wqc; wp.w[4]=Wkc; wp.w[5]=Wvc;
  repack_w3<<<dim3(2304, 6), 256, 0, stream>>>(wp, AL, AV);
  wcomb<<<dim3(256), 256, 0, stream>>>(Wgs, bgs, Wfu, bfu, WT, BT, ZP);

  gemm_conv<<<dim3(32, 12, 2), 256, 0, stream>>>(
      AL, AV, Xt, (const __bf16*)ZP, QST, KST, VS, QCT, KCT, VC,
      bqs, bks, bvs, bqc, bkc, bvc);

  qk_stats<<<dim3(512), 256, 0, stream>>>(QST, QCT, KST, KCT, PM, PL);
  stats_combine2<<<dim3(16, 4), 256, 0, stream>>>(PM, PL, MST, LST);

  fused_pv<<<dim3(512), 512, 0, stream>>>(
      QST, QCT, KST, KCT, VS, VC, MST, LST, GACC);

  gsum_reshape<<<dim3(4, 16, 4), 256, 0, stream>>>(GACC, GTS);

  tail_gemm<<<dim3(32, 2, 2), 256, 0, stream>>>(WT, GTS, Xt, BT, (float*)d_out);
}

// Round 10
// 413.783 us; speedup vs baseline: 1.1056x; 1.0626x over previous
//
#include <hip/hip_runtime.h>

typedef __bf16 bf16x4 __attribute__((ext_vector_type(4)));
typedef __bf16 bf16x8 __attribute__((ext_vector_type(8)));
typedef float  f32x4  __attribute__((ext_vector_type(4)));

#define HWSZ 4096
#define CCH  256
#define LOG2E 1.44269504088896340736f

__device__ __forceinline__ float exp2_fast(float x) {
#if __has_builtin(__builtin_amdgcn_exp2f)
  return __builtin_amdgcn_exp2f(x);
#else
  return exp2f(x);
#endif
}

// barrier that only drains LDS ops (lgkmcnt), letting global loads stay in
// flight across the barrier. Safe when the barrier only protects LDS state.
__device__ __forceinline__ void bar_lgkm() {
  asm volatile("s_waitcnt lgkmcnt(0)" ::: "memory");
  __builtin_amdgcn_s_barrier();
}

// stage 16B per lane into LDS; lane's data lands at lds_base + lane*16B
__device__ __forceinline__ void stage16(const __bf16* g, __bf16* ldsBase) {
#if __has_builtin(__builtin_amdgcn_global_load_lds)
  __builtin_amdgcn_global_load_lds(
      (const __attribute__((address_space(1))) void*)g,
      (__attribute__((address_space(3))) void*)ldsBase, 16, 0, 0);
#else
  int lane = threadIdx.x & 63;
  *(bf16x8*)(ldsBase + lane * 8) = *(const bf16x8*)g;
#endif
}

// XOR swizzle for 32-elem-row LDS tiles: phys 16B-chunk = logical ^ ((row>>1)&3).
#define SWZ_STAGE(lane) ((((lane) & 3) ^ (((lane) >> 3) & 3)) * 8)
#define SWZ_READ(quad, lane) ((((quad) ^ (((lane) >> 1) & 3))) * 8)

// ---------------------------------------------------------------------------
// Merged conv3x3 GEMM, implicit-im2col, 2-PHASE double-buffered (T3 minimum):
// tile t+1's global_load_lds issued BEFORE tile t's MFMAs; ONE barrier/k-step.
// by<8 -> A=AL (Qs,Ks,Vs,Qc from Fl), else A=AV (Kc,Vc from Fv). B staged
// directly from Xt [img][4096][256]: tap t=k0>>8 (dy,dx), border lanes read a
// zero page. LDS 32 KB (2 x (As 8K + Bs 8K)).  [validated R9: total -11us]
// ---------------------------------------------------------------------------
__global__ __launch_bounds__(256)
void gemm_conv(const __bf16* __restrict__ AL, const __bf16* __restrict__ AV,
               const __bf16* __restrict__ Xt, const __bf16* __restrict__ zp,
               __bf16* __restrict__ qst, __bf16* __restrict__ kst,
               __bf16* __restrict__ vs,  __bf16* __restrict__ qct,
               __bf16* __restrict__ kct, __bf16* __restrict__ vc,
               const float* __restrict__ bqs, const float* __restrict__ bks,
               const float* __restrict__ bvs, const float* __restrict__ bqc,
               const float* __restrict__ bkc, const float* __restrict__ bvc)
{
  __shared__ __align__(16) __bf16 smem[16384];   // 2 bufs x (As 4096 + Bs 4096)

  const int tid  = threadIdx.x;
  const int lane = tid & 63;
  const int w    = tid >> 6;
  const int wm   = (w >> 1) * 64;
  const int wn   = (w & 1) * 64;
  const int z    = blockIdx.z;
  const int by   = blockIdx.y;
  const int bn   = blockIdx.x * 128;
  const int K    = 2304;

  const bool isL = (by < 8);
  const int bm = (isL ? by : by - 8) * 128;
  const __bf16* Ab = isL ? AL : AV;
  const __bf16* Xb = Xt + (long)((isL ? 0 : 2) + z) * (HWSZ * CCH);

  f32x4 acc[4][4] = {};
  const int srow = lane >> 2;
  const int skc  = SWZ_STAGE(lane);
  const int quad = lane >> 4, l15 = lane & 15;
  const int rdo  = SWZ_READ(quad, lane);

  // stage tile (k0) into buffer base
  auto stage_tile = [&](int k0, __bf16* As, __bf16* Bs) {
    const int t9  = k0 >> 8;                 // tap 0..8 (uniform per k0)
    const int dy  = t9 / 3 - 1;
    const int dx  = t9 - (t9 / 3) * 3 - 1;
    const int off = dy * 64 + dx;
    const int ci0 = k0 & 255;
#pragma unroll
    for (int j = 0; j < 2; ++j) {
      int rbase = w * 32 + j * 16;
      stage16(Ab + (long)(bm + rbase + srow) * K + k0 + skc, As + rbase * 32);
    }
#pragma unroll
    for (int j = 0; j < 2; ++j) {
      int rbase = w * 32 + j * 16;
      int p = bn + rbase + srow;
      int y = p >> 6, x = p & 63;
      bool valid = ((unsigned)(y + dy) < 64u) && ((unsigned)(x + dx) < 64u);
      const __bf16* src = valid ? (Xb + (long)(p + off) * CCH + ci0 + skc) : zp;
      stage16(src, Bs + rbase * 32);
    }
  };

  // prologue: stage tile 0 into buf0
  stage_tile(0, smem, smem + 4096);
  asm volatile("s_waitcnt vmcnt(0)" ::: "memory");
  __builtin_amdgcn_s_barrier();

  for (int k0 = 0; k0 < K; k0 += 32) {
    const int cur = (k0 >> 5) & 1;
    __bf16* As = smem + cur * 8192;
    __bf16* Bs = As + 4096;
    // issue next tile's loads first — they fly under this tile's MFMAs
    const int nxt = k0 + 32;
    if (nxt < K) {
      __bf16* An = smem + (cur ^ 1) * 8192;
      stage_tile(nxt, An, An + 4096);
    }
    bf16x8 af[4], bfr[4];
#pragma unroll
    for (int t = 0; t < 4; ++t)
      af[t] = *(const bf16x8*)(As + (wm + t * 16 + l15) * 32 + rdo);
#pragma unroll
    for (int t = 0; t < 4; ++t)
      bfr[t] = *(const bf16x8*)(Bs + (wn + t * 16 + l15) * 32 + rdo);
    __builtin_amdgcn_s_setprio(1);
#pragma unroll
    for (int mt = 0; mt < 4; ++mt)
#pragma unroll
      for (int nt = 0; nt < 4; ++nt)
        acc[mt][nt] = __builtin_amdgcn_mfma_f32_16x16x32_bf16(af[mt], bfr[nt], acc[mt][nt], 0, 0, 0);
    __builtin_amdgcn_s_setprio(0);
    // next tile's loads landed (mine) + my LDS reads done; one barrier/iter
    asm volatile("s_waitcnt vmcnt(0) lgkmcnt(0)" ::: "memory");
    __builtin_amdgcn_s_barrier();
  }

#pragma unroll
  for (int mt = 0; mt < 4; ++mt) {
#pragma unroll
    for (int nt = 0; nt < 4; ++nt) {
#pragma unroll
      for (int r = 0; r < 4; ++r) {
        int m = bm + wm + mt * 16 + quad * 4 + r;
        int n = bn + wn + nt * 16 + l15;
        int g = m >> 8, mm = m & 255;
        const float* bias; __bf16* op; bool vlay;
        if (isL) {
          bias = (g == 0) ? bqs : (g == 1) ? bks : (g == 2) ? bvs : bqc;
          op   = (g == 0) ? qst : (g == 1) ? kst : (g == 2) ? vs  : qct;
          vlay = (g == 2);
        } else {
          bias = g ? bvc : bkc;
          op   = g ? vc  : kct;
          vlay = (g == 1);
        }
        float vv = acc[mt][nt][r] + bias[mm];
        if (vlay) op[(long)z * 1048576 + (long)mm * HWSZ + n] = (__bf16)vv;   // V: [c,p]
        else      op[(long)z * 1048576 + (long)n * CCH + mm] = (__bf16)vv;    // Q/K: [p,c]
      }
    }
  }
}

// ---------------------------------------------------------------------------
// qk_stats: partial column-softmax stats over HALF the i-range.
// 1-D grid 512: lid -> (g: z,br | ih | qb). Kres stride 260 (conflict-free).
// setprio REMOVED (R2->R6 A/B: fused_pv flat but total +14us with setprio
// here; consistent with m190's null-to-negative on lockstep MFMA loops).
// ---------------------------------------------------------------------------
__global__ __launch_bounds__(256)
void qk_stats(const __bf16* __restrict__ qs, const __bf16* __restrict__ qc,
              const __bf16* __restrict__ ks, const __bf16* __restrict__ kc,
              float* __restrict__ pm, float* __restrict__ pl)
{
  __shared__ __align__(16) __bf16 Kres[64 * 260];
  __shared__ float wm_[4][64], wl_[4][64];

  const int tid = threadIdx.x, lane = tid & 63, w = tid >> 6;
  const int quad = lane >> 4, l15 = lane & 15;
  const int lid = blockIdx.x;
  const int g = lid & 3;
  const int z = g & 1, br = g >> 1;
  const int ih = (lid >> 2) & 1;
  const int qb = (lid >> 3) * 64;
  const __bf16* Qt = (br ? qc : qs) + (long)z * 1048576;
  const __bf16* Kt = (br ? kc : ks) + (long)z * 1048576;

  for (int idx = tid; idx < 2048; idx += 256) {
    int r = idx >> 5, c8 = (idx & 31) * 8;
    *(bf16x8*)(Kres + r * 260 + c8) = *(const bf16x8*)(Kt + (long)(qb + r) * 256 + c8);
  }
  __syncthreads();

  float rm[4], rl[4];
#pragma unroll
  for (int nt = 0; nt < 4; ++nt) { rm[nt] = -3.0e38f; rl[nt] = 0.f; }

  for (int it = 0; it < 8; ++it) {
    const int i0 = ih * 2048 + it * 256 + w * 64;
    f32x4 accS[4][4] = {};
#pragma unroll
    for (int cs = 0; cs < 256; cs += 32) {
      bf16x8 a[4], b[4];
#pragma unroll
      for (int mt = 0; mt < 4; ++mt)
        a[mt] = *(const bf16x8*)(Qt + (long)(i0 + mt * 16 + l15) * 256 + cs + quad * 8);
#pragma unroll
      for (int nt = 0; nt < 4; ++nt)
        b[nt] = *(const bf16x8*)(Kres + (nt * 16 + l15) * 260 + cs + quad * 8);
#pragma unroll
      for (int mt = 0; mt < 4; ++mt)
#pragma unroll
        for (int nt = 0; nt < 4; ++nt)
          accS[mt][nt] = __builtin_amdgcn_mfma_f32_16x16x32_bf16(a[mt], b[nt], accS[mt][nt], 0, 0, 0);
    }
#pragma unroll
    for (int nt = 0; nt < 4; ++nt) {
      float mx = -3.0e38f;
#pragma unroll
      for (int mt = 0; mt < 4; ++mt)
#pragma unroll
        for (int r = 0; r < 4; ++r) mx = fmaxf(mx, accS[mt][nt][r]);
      float sl = 0.f;
#pragma unroll
      for (int mt = 0; mt < 4; ++mt)
#pragma unroll
        for (int r = 0; r < 4; ++r) sl += exp2_fast((accS[mt][nt][r] - mx) * LOG2E);
#pragma unroll
      for (int d = 16; d <= 32; d <<= 1) {
        float om = __shfl_xor(mx, d, 64);
        float ol = __shfl_xor(sl, d, 64);
        float nm = fmaxf(mx, om);
        sl = sl * exp2_fast((mx - nm) * LOG2E) + ol * exp2_fast((om - nm) * LOG2E);
        mx = nm;
      }
      float nm = fmaxf(rm[nt], mx);
      rl[nt] = rl[nt] * exp2_fast((rm[nt] - nm) * LOG2E) + sl * exp2_fast((mx - nm) * LOG2E);
      rm[nt] = nm;
    }
  }
  if (lane < 16) {
#pragma unroll
    for (int nt = 0; nt < 4; ++nt) { wm_[w][nt * 16 + lane] = rm[nt]; wl_[w][nt * 16 + lane] = rl[nt]; }
  }
  __syncthreads();
  if (tid < 64) {
    float m = -3.0e38f;
#pragma unroll
    for (int ww = 0; ww < 4; ++ww) m = fmaxf(m, wm_[ww][tid]);
    float l = 0.f;
#pragma unroll
    for (int ww = 0; ww < 4; ++ww)
      l += wl_[ww][tid] * exp2_fast((wm_[ww][tid] - m) * LOG2E);
    long o = ((long)ih * 4 + br * 2 + z) * 4096 + qb + tid;
    pm[o] = m;
    pl[o] = l;
  }
}

// combine the two i-half partials -> final m, 1/l. grid (16, 4 zbr), 256 thr.
__global__ void stats_combine2(const float* __restrict__ pm, const float* __restrict__ pl,
                               float* __restrict__ mst, float* __restrict__ lst) {
  int q = blockIdx.x * 256 + threadIdx.x;
  int zbr = blockIdx.y;
  float m0 = pm[(long)zbr * 4096 + q],        l0 = pl[(long)zbr * 4096 + q];
  float m1 = pm[(long)(4 + zbr) * 4096 + q],  l1 = pl[(long)(4 + zbr) * 4096 + q];
  float m = fmaxf(m0, m1);
  float l = l0 * exp2_fast((m0 - m) * LOG2E) + l1 * exp2_fast((m1 - m) * LOG2E);
  mst[(long)zbr * 4096 + q] = m;
  lst[(long)zbr * 4096 + q] = 1.0f / l;
}

// ---------------------------------------------------------------------------
// Fused recompute-S PV, 8-wave blocks (512 thr), qc0 chunk 256 — exact R6/R9
// form (best measured 137-138 us; six levers tried, all null or regressions).
// K and V direct global->reg (L2-resident via lid&7 XCD pinning). Pl exchange
// barriers lgkm-only; first 128 V columns prefetched before the P-write
// barrier. LDS = Qres+Pl = 66.6 KB -> 2 blocks/CU.
// ---------------------------------------------------------------------------
__global__ __launch_bounds__(512, 4)
void fused_pv(const __bf16* __restrict__ qs, const __bf16* __restrict__ qc,
              const __bf16* __restrict__ ks, const __bf16* __restrict__ kc,
              const __bf16* __restrict__ vs, const __bf16* __restrict__ vc,
              const float* __restrict__ mst, const float* __restrict__ lst,
              float* __restrict__ gacc)
{
  __shared__ __align__(16) __bf16 Qres[64 * 260];   // 33.3 KB (conflict-free)
  __shared__ __align__(16) __bf16 Pl[64 * 260];     // 33.3 KB (k-chunk 256)

  const int tid = threadIdx.x, lane = tid & 63, w = tid >> 6;   // w in [0,8)
  const int quad = lane >> 4, l15 = lane & 15;
  const int lid = blockIdx.x;
  const int g   = lid & 7;
  const int zbr = g >> 1;
  const int qh  = g & 1;
  const int bi  = (lid >> 3) * 64;
  const int br = zbr >> 1, z = zbr & 1;
  const __bf16* Qt = (br ? qc : qs) + (long)z * 1048576;
  const __bf16* Kt = (br ? kc : ks) + (long)z * 1048576;
  const __bf16* Vv = (br ? vc : vs) + (long)z * 1048576;
  const float* msp = mst + (long)zbr * 4096;
  const float* lsp = lst + (long)zbr * 4096;
  float* go = gacc + ((long)qh * 4 + zbr) * 1048576;

  for (int idx = tid; idx < 2048; idx += 512) {
    int r = idx >> 5, c8 = (idx & 31) * 8;
    *(bf16x8*)(Qres + r * 260 + c8) = *(const bf16x8*)(Qt + (long)(bi + r) * 256 + c8);
  }
  __syncthreads();

  f32x4 accO[4][2] = {};
  const int q0 = qh * 2048;
  // per-lane V row pointers (output channels j = w*32 + nt*16 + l15)
  const __bf16* Vl0 = Vv + (long)(w * 32 + l15) * 4096 + quad * 8;
  const __bf16* Vl1 = Vl0 + (long)16 * 4096;

  for (int qc0 = q0; qc0 < q0 + 2048; qc0 += 256) {
    // --- S phase: K direct global->reg, wave k-slice 32 ---
    f32x4 accS[4][2] = {};
    const __bf16* Kl0 = Kt + (long)(qc0 + w * 32 + l15) * 256 + quad * 8;
    const __bf16* Kl1 = Kl0 + (long)16 * 256;
#pragma unroll
    for (int cs = 0; cs < 256; cs += 32) {
      bf16x8 aq[4];
      bf16x8 bk0 = *(const bf16x8*)(Kl0 + cs);
      bf16x8 bk1 = *(const bf16x8*)(Kl1 + cs);
#pragma unroll
      for (int mt = 0; mt < 4; ++mt)
        aq[mt] = *(const bf16x8*)(Qres + (mt * 16 + l15) * 260 + cs + quad * 8);
      __builtin_amdgcn_s_setprio(1);
#pragma unroll
      for (int mt = 0; mt < 4; ++mt) {
        accS[mt][0] = __builtin_amdgcn_mfma_f32_16x16x32_bf16(aq[mt], bk0, accS[mt][0], 0, 0, 0);
        accS[mt][1] = __builtin_amdgcn_mfma_f32_16x16x32_bf16(aq[mt], bk1, accS[mt][1], 0, 0, 0);
      }
      __builtin_amdgcn_s_setprio(0);
    }
    // prefetch: stats + first 128 V columns of this chunk (consumed after bars)
    float mq0 = msp[qc0 + w * 32 + l15],      lq0 = lsp[qc0 + w * 32 + l15];
    float mq1 = msp[qc0 + w * 32 + 16 + l15], lq1 = lsp[qc0 + w * 32 + 16 + l15];
    bf16x8 pv00 = *(const bf16x8*)(Vl0 + qc0);
    bf16x8 pv01 = *(const bf16x8*)(Vl1 + qc0);
    bf16x8 pv10 = *(const bf16x8*)(Vl0 + qc0 + 32);
    bf16x8 pv11 = *(const bf16x8*)(Vl1 + qc0 + 32);
    bf16x8 pv20 = *(const bf16x8*)(Vl0 + qc0 + 64);
    bf16x8 pv21 = *(const bf16x8*)(Vl1 + qc0 + 64);
    bf16x8 pv30 = *(const bf16x8*)(Vl0 + qc0 + 96);
    bf16x8 pv31 = *(const bf16x8*)(Vl1 + qc0 + 96);
    bar_lgkm();   // all waves' previous V-phase Pl reads complete
    // P = exp(S - m_q)*linv_q -> Pl
#pragma unroll
    for (int nt = 0; nt < 2; ++nt) {
      int q = w * 32 + nt * 16 + l15;
      float mq = nt ? mq1 : mq0, lq = nt ? lq1 : lq0;
#pragma unroll
      for (int mt = 0; mt < 4; ++mt)
#pragma unroll
        for (int r = 0; r < 4; ++r) {
          int i = mt * 16 + quad * 4 + r;
          Pl[i * 260 + q] = (__bf16)(exp2_fast((accS[mt][nt][r] - mq) * LOG2E) * lq);
        }
    }
    bar_lgkm();   // Pl visible to all waves
    // --- V phase: direct-reg V, no barriers ---
#pragma unroll
    for (int qs0 = 0; qs0 < 256; qs0 += 32) {
      bf16x8 ap[4], bv0, bv1;
      if (qs0 == 0)       { bv0 = pv00; bv1 = pv01; }
      else if (qs0 == 32) { bv0 = pv10; bv1 = pv11; }
      else if (qs0 == 64) { bv0 = pv20; bv1 = pv21; }
      else if (qs0 == 96) { bv0 = pv30; bv1 = pv31; }
      else {
        bv0 = *(const bf16x8*)(Vl0 + qc0 + qs0);
        bv1 = *(const bf16x8*)(Vl1 + qc0 + qs0);
      }
#pragma unroll
      for (int mt = 0; mt < 4; ++mt)
        ap[mt] = *(const bf16x8*)(Pl + (mt * 16 + l15) * 260 + qs0 + quad * 8);
      __builtin_amdgcn_s_setprio(1);
#pragma unroll
      for (int mt = 0; mt < 4; ++mt) {
        accO[mt][0] = __builtin_amdgcn_mfma_f32_16x16x32_bf16(ap[mt], bv0, accO[mt][0], 0, 0, 0);
        accO[mt][1] = __builtin_amdgcn_mfma_f32_16x16x32_bf16(ap[mt], bv1, accO[mt][1], 0, 0, 0);
      }
      __builtin_amdgcn_s_setprio(0);
    }
  }
  // natural-layout fp32 partial store (coalesced 64B segments)
#pragma unroll
  for (int mt = 0; mt < 4; ++mt)
#pragma unroll
    for (int nt = 0; nt < 2; ++nt)
#pragma unroll
      for (int r = 0; r < 4; ++r) {
        int i = mt * 16 + quad * 4 + r;
        int j = w * 32 + nt * 16 + l15;
        go[(long)(bi + i) * 256 + j] = accO[mt][nt][r];
      }
}

// ---------------------------------------------------------------------------
// Sum the two q-half partials and write GTS in raw-reshape layout via LDS
// transpose. grid (jg 4, v 16, zbr 4), 256 threads.
__global__ __launch_bounds__(256)
void gsum_reshape(const float* __restrict__ ga, __bf16* __restrict__ gt) {
  __shared__ __bf16 lds[64 * 260];
  const int t = threadIdx.x, lane = t & 63, w = t >> 6;
  const int zbr = blockIdx.z;
  const int v   = blockIdx.y;
  const int jg  = blockIdx.x;
  const float* g0 = ga + (long)zbr * 1048576;
  const float* g1 = g0 + 4194304;
  for (int ci0 = 0; ci0 < 256; ci0 += 4) {
    int ci = ci0 + w;
    long src = (long)(ci * 16 + v) * 256 + jg * 64 + lane;
    lds[lane * 260 + ci] = (__bf16)(g0[src] + g1[src]);
  }
  __syncthreads();
  __bf16* out = gt + (long)zbr * 1048576 + ((long)v * 256 + jg * 64) * 256;
#pragma unroll
  for (int pp = 0; pp < 8; ++pp) {
    int idx = pp * 256 + t;
    int row = idx >> 5, c8 = (idx & 31) * 8;
    *(bf16x8*)(out + (long)row * 256 + c8) = *(const bf16x8*)(lds + row * 260 + c8);
  }
}

// ---------------------------------------------------------------------------
// Weight fold: WT = [Wfu_l*Wgs | Wfu_v*Wgs | Wfu_l | Wfu_v] (bf16 [256][1024]),
// biasT[co] = bfu[co] + sum_c (Wfu[co][c]+Wfu[co][c+256]) * bgs[c].
// Also zeroes the 256-B zero page used by gemm_conv border lanes.
__global__ __launch_bounds__(256)
void wcomb(const float* __restrict__ Wgs, const float* __restrict__ bgs,
           const float* __restrict__ Wfu, const float* __restrict__ bfu,
           __bf16* __restrict__ WT, float* __restrict__ biasT,
           float* __restrict__ zp)
{
  const int co = blockIdx.x, t = threadIdx.x;
  if (co == 0 && t < 64) zp[t] = 0.f;
  const float* wrow = Wfu + (long)co * 512;
  float accs = 0.f, accc = 0.f;
  for (int c = 0; c < 256; ++c) {
    float gv = Wgs[(long)c * 256 + t];
    accs = fmaf(wrow[c], gv, accs);
    accc = fmaf(wrow[c + 256], gv, accc);
  }
  __bf16* o = WT + (long)co * 1024;
  o[t]       = (__bf16)accs;
  o[256 + t] = (__bf16)accc;
  o[512 + t] = (__bf16)wrow[t];
  o[768 + t] = (__bf16)wrow[256 + t];
  __shared__ float red[256];
  red[t] = (wrow[t] + wrow[t + 256]) * bgs[t];
  __syncthreads();
  for (int s = 128; s > 0; s >>= 1) {
    if (t < s) red[t] += red[t + s];
    __syncthreads();
  }
  if (t == 0) biasT[co] = bfu[co] + red[0];
}

// ---------------------------------------------------------------------------
// Tail GEMM, 2-PHASE double-buffered, m64 x n128 tiles -> grid (32,4,2) =
// 256 blocks (was 128 = half the GPU idle). out[z][co][p] =
// sum_k WT[co][k]*Bcat[z][p][k] + biasT[co]; Bcat k-groups: 0 GTS_s, 1 GTS_c,
// 2 Xt(Fl), 3 Xt(Fv). 4 waves, wave tile 32x64 (acc[2][4]). LDS 24 KB.
// ---------------------------------------------------------------------------
__global__ __launch_bounds__(256)
void tail_gemm(const __bf16* __restrict__ WT, const __bf16* __restrict__ GTS,
               const __bf16* __restrict__ Xt, const float* __restrict__ biasT,
               float* __restrict__ out)
{
  __shared__ __align__(16) __bf16 smem[12288];   // 2 bufs x (As 2048 + Bs 4096)

  const int tid  = threadIdx.x;
  const int lane = tid & 63;
  const int w    = tid >> 6;
  const int wm   = (w >> 1) * 32;
  const int wn   = (w & 1) * 64;
  const int z    = blockIdx.z;
  const int bm   = blockIdx.y * 64;
  const int bn   = blockIdx.x * 128;

  const __bf16* Bsel[4] = {
    GTS + (long)z * 1048576, GTS + (long)(2 + z) * 1048576,
    Xt  + (long)z * 1048576, Xt  + (long)(2 + z) * 1048576
  };

  f32x4 acc[2][4] = {};
  const int srow = lane >> 2;
  const int skc  = SWZ_STAGE(lane);
  const int quad = lane >> 4, l15 = lane & 15;
  const int rdo  = SWZ_READ(quad, lane);

  auto stage_tile = [&](int k0, __bf16* As, __bf16* Bs) {
    const __bf16* Bb = Bsel[k0 >> 8];
    const int kk = k0 & 255;
    // A: 64 rows, wave w stages rows w*16..w*16+15
    stage16(WT + (long)(bm + w * 16 + srow) * 1024 + k0 + skc, As + (w * 16) * 32);
    // B: 128 rows, wave w stages rows w*32..w*32+31
#pragma unroll
    for (int j = 0; j < 2; ++j) {
      int rbase = w * 32 + j * 16;
      stage16(Bb + (long)(bn + rbase + srow) * 256 + kk + skc, Bs + rbase * 32);
    }
  };

  stage_tile(0, smem, smem + 2048);
  asm volatile("s_waitcnt vmcnt(0)" ::: "memory");
  __builtin_amdgcn_s_barrier();

  for (int k0 = 0; k0 < 1024; k0 += 32) {
    const int cur = (k0 >> 5) & 1;
    __bf16* As = smem + cur * 6144;
    __bf16* Bs = As + 2048;
    const int nxt = k0 + 32;
    if (nxt < 1024) {
      __bf16* An = smem + (cur ^ 1) * 6144;
      stage_tile(nxt, An, An + 2048);
    }
    bf16x8 af[2], bfr[4];
#pragma unroll
    for (int t = 0; t < 2; ++t)
      af[t] = *(const bf16x8*)(As + (wm + t * 16 + l15) * 32 + rdo);
#pragma unroll
    for (int t = 0; t < 4; ++t)
      bfr[t] = *(const bf16x8*)(Bs + (wn + t * 16 + l15) * 32 + rdo);
    __builtin_amdgcn_s_setprio(1);
#pragma unroll
    for (int mt = 0; mt < 2; ++mt)
#pragma unroll
      for (int nt = 0; nt < 4; ++nt)
        acc[mt][nt] = __builtin_amdgcn_mfma_f32_16x16x32_bf16(af[mt], bfr[nt], acc[mt][nt], 0, 0, 0);
    __builtin_amdgcn_s_setprio(0);
    asm volatile("s_waitcnt vmcnt(0) lgkmcnt(0)" ::: "memory");
    __builtin_amdgcn_s_barrier();
  }

#pragma unroll
  for (int mt = 0; mt < 2; ++mt)
#pragma unroll
    for (int nt = 0; nt < 4; ++nt)
#pragma unroll
      for (int r = 0; r < 4; ++r) {
        int m = bm + wm + mt * 16 + quad * 4 + r;
        int n = bn + wn + nt * 16 + l15;
        out[((long)z * 256 + m) * HWSZ + n] = acc[mt][nt][r] + biasT[m];
      }
}

// ---------------------------------------------------------------------------
// Fl/Fv [b][256][4096] fp32 -> Xt [img][4096][256] bf16 (Fl b0, Fl b1, Fv b0, Fv b1)
__global__ void transpose_cvt(const float* __restrict__ F0, const float* __restrict__ F1,
                              __bf16* __restrict__ Xt) {
  __shared__ float tile[32][33];
  int img = blockIdx.z;
  const float* src = (img < 2 ? F0 : F1) + (long)(img & 1) * (CCH * HWSZ);
  __bf16* dst = Xt + (long)img * (HWSZ * CCH);
  int p0 = blockIdx.x * 32, c0 = blockIdx.y * 32;
  int tx = threadIdx.x, ty = threadIdx.y;
#pragma unroll
  for (int j = 0; j < 32; j += 8)
    tile[ty + j][tx] = src[(long)(c0 + ty + j) * HWSZ + p0 + tx];
  __syncthreads();
#pragma unroll
  for (int j = 0; j < 32; j += 8)
    dst[(long)(p0 + ty + j) * CCH + c0 + tx] = (__bf16)tile[tx][ty + j];
}

// W[co][ci][3][3] fp32 -> A[co][t*256+ci] bf16, stacked AL (Wqs,Wks,Wvs,Wqc), AV (Wkc,Wvc)
struct W6 { const float* w[6]; };
__global__ void repack_w3(W6 wp, __bf16* __restrict__ AL, __bf16* __restrict__ AV) {
  int zi = blockIdx.y;
  int e = blockIdx.x * 256 + threadIdx.x;
  int co = e / 2304;
  int rem = e - co * 2304;
  int t = rem >> 8, ci = rem & 255;
  float v = wp.w[zi][(long)co * 2304 + ci * 9 + t];
  __bf16* dst = (zi < 4) ? (AL + (long)zi * 256 * 2304) : (AV + (long)(zi - 4) * 256 * 2304);
  dst[(long)co * 2304 + rem] = (__bf16)v;
}

// ---------------------------------------------------------------------------
extern "C" void kernel_launch(void* const* d_in, const int* in_sizes, int n_in,
                              void* d_out, int out_size, void* d_ws, size_t ws_size,
                              hipStream_t stream) {
  const float* Fl  = (const float*)d_in[0];
  const float* Fv  = (const float*)d_in[1];
  const float* Wqs = (const float*)d_in[2];  const float* bqs = (const float*)d_in[3];
  const float* Wks = (const float*)d_in[4];  const float* bks = (const float*)d_in[5];
  const float* Wvs = (const float*)d_in[6];  const float* bvs = (const float*)d_in[7];
  const float* Wqc = (const float*)d_in[8];  const float* bqc = (const float*)d_in[9];
  const float* Wkc = (const float*)d_in[10]; const float* bkc = (const float*)d_in[11];
  const float* Wvc = (const float*)d_in[12]; const float* bvc = (const float*)d_in[13];
  const float* Wgs = (const float*)d_in[14]; const float* bgs = (const float*)d_in[15];
  const float* Wfu = (const float*)d_in[16]; const float* bfu = (const float*)d_in[17];

  char* ws = (char*)d_ws;
  size_t off = 0;
  auto take = [&](size_t bytes) -> void* {
    void* p = ws + off; off = (off + bytes + 255) & ~(size_t)255; return p;
  };
  __bf16* QST  = (__bf16*)take(4194304);   // Qs^T  [b][4096][256]
  __bf16* KST  = (__bf16*)take(4194304);
  __bf16* QCT  = (__bf16*)take(4194304);
  __bf16* KCT  = (__bf16*)take(4194304);
  __bf16* VS   = (__bf16*)take(4194304);   // Vs    [b][256][4096]
  __bf16* VC   = (__bf16*)take(4194304);
  __bf16* GTS  = (__bf16*)take(8388608);   // G (reshape layout) [br*2+z][4096][256]
  __bf16* AL   = (__bf16*)take(4718592);   // conv weights [1024][2304]
  __bf16* AV   = (__bf16*)take(2359296);   // [512][2304]
  __bf16* WT   = (__bf16*)take(524288);    // folded tail weights [256][1024]
  float*  BT   = (float*)take(1024);       // folded tail bias [256]
  float*  ZP   = (float*)take(256);        // zero page for conv border lanes
  float*  MST  = (float*)take(65536);      // [br*2+z][4096]
  float*  LST  = (float*)take(65536);
  float*  PM   = (float*)take(131072);     // partial stats [ih][zbr][4096]
  float*  PL   = (float*)take(131072);
  __bf16* Xt   = (__bf16*)take(8388608);   // [img][4096][256] — alive through tail
  size_t ovl = off;                        // GACC after all persistent buffers
  float* GACC = (float*)(ws + ovl);        // [2 qh][4 zbr][4096*256] fp32 = 32 MB
  size_t need = ovl + 33554432;
  if (ws_size < need) return;

  transpose_cvt<<<dim3(128, 8, 4), dim3(32, 8), 0, stream>>>(Fl, Fv, Xt);
  W6 wp; wp.w[0]=Wqs; wp.w[1]=Wks; wp.w[2]=Wvs; wp.w[3]=Wqc; wp.w[4]=Wkc; wp.w[5]=Wvc;
  repack_w3<<<dim3(2304, 6), 256, 0, stream>>>(wp, AL, AV);
  wcomb<<<dim3(256), 256, 0, stream>>>(Wgs, bgs, Wfu, bfu, WT, BT, ZP);

  gemm_conv<<<dim3(32, 12, 2), 256, 0, stream>>>(
      AL, AV, Xt, (const __bf16*)ZP, QST, KST, VS, QCT, KCT, VC,
      bqs, bks, bvs, bqc, bkc, bvc);

  qk_stats<<<dim3(512), 256, 0, stream>>>(QST, QCT, KST, KCT, PM, PL);
  stats_combine2<<<dim3(16, 4), 256, 0, stream>>>(PM, PL, MST, LST);

  fused_pv<<<dim3(512), 512, 0, stream>>>(
      QST, QCT, KST, KCT, VS, VC, MST, LST, GACC);

  gsum_reshape<<<dim3(4, 16, 4), 256, 0, stream>>>(GACC, GTS);

  tail_gemm<<<dim3(32, 4, 2), 256, 0, stream>>>(WT, GTS, Xt, BT, (float*)d_out);
}